// Round 3
// baseline (2146.721 us; speedup 1.0000x reference)
//
#include <hip/hip_runtime.h>
#include <hip/hip_bf16.h>

typedef __bf16 bf16_t;
typedef __attribute__((ext_vector_type(8))) __bf16 bf16x8;
typedef __attribute__((ext_vector_type(4))) float floatx4;

// Problem constants: B=4, T=2048, C=2048, H=16, D=128, QKV_DIM=6144, QKVZ=8192, BT=8192

// ---------------- cast fp32 -> bf16 (vectorized) ----------------
__global__ __launch_bounds__(256) void k_cast_bf16(const float* __restrict__ in,
                                                   bf16_t* __restrict__ out) {
  long i = ((long)blockIdx.x * 256 + threadIdx.x) * 8;
  const float4 a = *(const float4*)(in + i);
  const float4 b = *(const float4*)(in + i + 4);
  bf16x8 o;
  o[0] = (bf16_t)a.x; o[1] = (bf16_t)a.y; o[2] = (bf16_t)a.z; o[3] = (bf16_t)a.w;
  o[4] = (bf16_t)b.x; o[5] = (bf16_t)b.y; o[6] = (bf16_t)b.z; o[7] = (bf16_t)b.w;
  *(bf16x8*)(out + i) = o;
}

// ---------------- transpose + cast fp32 -> bf16 ----------------
// in: R x C row-major fp32, out: C x R row-major bf16. R,C multiples of 32.
__global__ void k_transpose_cast(const float* __restrict__ in, bf16_t* __restrict__ out,
                                 int R, int Ccols) {
  __shared__ float tile[32][33];
  int c0 = blockIdx.x * 32, r0 = blockIdx.y * 32;
  for (int i = threadIdx.y; i < 32; i += 8)
    tile[i][threadIdx.x] = in[(long)(r0 + i) * Ccols + c0 + threadIdx.x];
  __syncthreads();
  for (int i = threadIdx.y; i < 32; i += 8)
    out[(long)(c0 + i) * R + r0 + threadIdx.x] = (bf16_t)tile[threadIdx.x][i];
}

// small fp32 transpose (for W_b / W_a: 2048x16 -> 16x2048)
__global__ void k_transpose_f32(const float* __restrict__ in, float* __restrict__ out,
                                int R, int Ccols) {
  int r = blockIdx.x * blockDim.x + threadIdx.x;
  if (r < R)
    for (int c = 0; c < Ccols; ++c) out[(long)c * R + r] = in[(long)r * Ccols + c];
}

// ---------------- beta/alpha: sigmoid(x @ W) ----------------
// WbT/WaT are 16 x 2048 (transposed). beta/alpha layout (B,H,T).
__global__ __launch_bounds__(256) void k_beta_alpha(const float* __restrict__ x,
                                                    const float* __restrict__ WbT,
                                                    const float* __restrict__ WaT,
                                                    float* __restrict__ beta,
                                                    float* __restrict__ alpha) {
  int row = blockIdx.x;  // b*T + t
  __shared__ float xs[2048];
  for (int i = threadIdx.x; i < 2048; i += 256) xs[i] = x[(long)row * 2048 + i];
  __syncthreads();
  int wave = threadIdx.x >> 6, lane = threadIdx.x & 63;
  for (int o = wave * 8; o < wave * 8 + 8; ++o) {
    const float* W = (o < 16) ? (WbT + (long)o * 2048) : (WaT + (long)(o - 16) * 2048);
    float s = 0.f;
    for (int k2 = lane; k2 < 2048; k2 += 64) s += xs[k2] * W[k2];
    for (int off = 32; off; off >>= 1) s += __shfl_down(s, off);
    if (lane == 0) {
      float sig = 1.f / (1.f + expf(-s));
      int b = row >> 11, t = row & 2047;
      int h = (o < 16) ? o : (o - 16);
      float* dst = (o < 16) ? beta : alpha;
      dst[((long)(b * 16 + h)) * 2048 + t] = sig;
    }
  }
}

// ---------------- bf16 MFMA GEMM: C = A @ Bt^T ----------------
// A: M x K row-major bf16. Bt: N x K row-major bf16. C: M x N row-major OUT_T.
// BM=BN=128, BK=32; 256 threads (4 waves, 2x2), wave tile 64x64 via 4x4 16x16x32 frags.
template <typename OUT_T>
__global__ __launch_bounds__(256) void k_gemm_bt(const bf16_t* __restrict__ A,
                                                 const bf16_t* __restrict__ Bt,
                                                 OUT_T* __restrict__ C, int M, int N, int K) {
  constexpr int BK = 32;
  __shared__ alignas(16) bf16_t As[128][BK + 8];
  __shared__ alignas(16) bf16_t Bs[128][BK + 8];
  const int m0 = blockIdx.y * 128, n0 = blockIdx.x * 128;
  const int tid = threadIdx.x;
  const int wave = tid >> 6, lane = tid & 63;
  const int wr = wave >> 1, wc = wave & 1;
  const int lrow = lane & 15, lk = (lane >> 4) << 3;  // frag row, k elem offset
  floatx4 acc[4][4] = {};
  const int srow = tid >> 2, scol = (tid & 3) * 8;  // staging: 2 x 16B per thread per array
  const bf16_t* aptr = A + (long)(m0 + srow) * K + scol;
  const bf16_t* bptr = Bt + (long)(n0 + srow) * K + scol;
  const long half = 64 * (long)K;

  for (int k0 = 0; k0 < K; k0 += BK) {
    bf16x8 av0 = *(const bf16x8*)(aptr + k0);
    bf16x8 av1 = *(const bf16x8*)(aptr + half + k0);
    bf16x8 bv0 = *(const bf16x8*)(bptr + k0);
    bf16x8 bv1 = *(const bf16x8*)(bptr + half + k0);
    __syncthreads();  // previous compute done before overwrite
    *(bf16x8*)&As[srow][scol] = av0;
    *(bf16x8*)&As[srow + 64][scol] = av1;
    *(bf16x8*)&Bs[srow][scol] = bv0;
    *(bf16x8*)&Bs[srow + 64][scol] = bv1;
    __syncthreads();
    bf16x8 af[4], bfr[4];
#pragma unroll
    for (int i = 0; i < 4; i++) af[i] = *(const bf16x8*)&As[wr * 64 + i * 16 + lrow][lk];
#pragma unroll
    for (int i = 0; i < 4; i++) bfr[i] = *(const bf16x8*)&Bs[wc * 64 + i * 16 + lrow][lk];
#pragma unroll
    for (int mi = 0; mi < 4; mi++)
#pragma unroll
      for (int ni = 0; ni < 4; ni++)
        acc[mi][ni] = __builtin_amdgcn_mfma_f32_16x16x32_bf16(af[mi], bfr[ni], acc[mi][ni], 0, 0, 0);
  }
  // Epilogue: C/D layout row=(lane>>4)*4+r, col=lane&15  [m89-verified]
  const int crow_base = m0 + wr * 64 + (lane >> 4) * 4;
  const int ccol = n0 + wc * 64 + (lane & 15);
#pragma unroll
  for (int mi = 0; mi < 4; mi++)
#pragma unroll
    for (int ni = 0; ni < 4; ni++)
#pragma unroll
      for (int r = 0; r < 4; r++)
        C[(long)(crow_base + mi * 16 + r) * N + ccol + ni * 16] = (OUT_T)acc[mi][ni][r];
}

// ---------------- depthwise causal conv + SiLU + l2norm -> q,k,v ----------------
// qkvz: (B*T, 8192) bf16. conv_w: (6144,1,4) fp32. q,k,v out: (B,H,T,D) bf16.
// Reads only columns 0..6143 of each qkvz row (z columns 6144..8191 untouched).
__global__ __launch_bounds__(256) void k_conv(const bf16_t* __restrict__ qkvz,
                                              const float* __restrict__ conv_w,
                                              bf16_t* __restrict__ q, bf16_t* __restrict__ k,
                                              bf16_t* __restrict__ v) {
  int row = blockIdx.x;  // b*T + t
  int b = row >> 11, t = row & 2047;
  __shared__ float ys[6144];
  __shared__ float gsum[32][9];
  __shared__ float norms[32];
  for (int c = threadIdx.x; c < 6144; c += 256) {
    float acc2 = 0.f;
#pragma unroll
    for (int w2 = 0; w2 < 4; ++w2) {
      int tt = t - 3 + w2;
      if (tt >= 0) acc2 += (float)qkvz[((long)(b * 2048 + tt)) * 8192 + c] * conv_w[c * 4 + w2];
    }
    ys[c] = acc2 / (1.f + expf(-acc2));  // silu
  }
  __syncthreads();
  {  // 32 groups (16 q + 16 k) of 128 channels, 8 threads per group
    int g = threadIdx.x >> 3, j = threadIdx.x & 7;
    float s = 0.f;
#pragma unroll
    for (int e = 0; e < 16; ++e) {
      float yv = ys[g * 128 + j * 16 + e];
      s += yv * yv;
    }
    gsum[g][j] = s;
  }
  __syncthreads();
  if (threadIdx.x < 32) {
    float s = 0.f;
#pragma unroll
    for (int j = 0; j < 8; j++) s += gsum[threadIdx.x][j];
    norms[threadIdx.x] = 1.f / fmaxf(sqrtf(s), 1e-12f);
  }
  __syncthreads();
  for (int c = threadIdx.x; c < 6144; c += 256) {
    float yv = ys[c];
    if (c < 2048) {
      int h = c >> 7, d = c & 127;
      q[(((long)(b * 16 + h)) * 2048 + t) * 128 + d] = (bf16_t)(yv * norms[h]);
    } else if (c < 4096) {
      int cc = c - 2048, h = cc >> 7, d = cc & 127;
      k[(((long)(b * 16 + h)) * 2048 + t) * 128 + d] = (bf16_t)(yv * norms[16 + h]);
    } else {
      int cc = c - 4096, h = cc >> 7, d = cc & 127;
      v[(((long)(b * 16 + h)) * 2048 + t) * 128 + d] = (bf16_t)yv;
    }
  }
}

// ---------------- sequential gated scan ----------------
// grid (64 bh, 8 dvc). Block 256: thread = (g = tid>>4 : 16 dk-groups of 8, dvi = tid&15).
// state[dk][dv] = a*state + b*k[dk]*v[dv]; out[dv] = sum_dk q[dk]*state.
// out: STRIDED fp32, row (b*2048+t) at so + row*4096, cols h*128+dv  (lives in qkvz's
// dead qkv region; z columns = bytes [12288,16384) of each 16KB row are untouched).
__global__ __launch_bounds__(256) void k_scan(const bf16_t* __restrict__ q,
                                              const bf16_t* __restrict__ k,
                                              const bf16_t* __restrict__ v,
                                              const float* __restrict__ beta,
                                              const float* __restrict__ alpha,
                                              float* __restrict__ out) {
  int bh = blockIdx.x, dvc = blockIdx.y;
  int b = bh >> 4, h = bh & 15;
  int tid = threadIdx.x;
  int dvi = tid & 15, g = tid >> 4;
  int dv = dvc * 16 + dvi;
  const bf16_t* kb = k + (long)bh * 2048 * 128;
  const bf16_t* qb = q + (long)bh * 2048 * 128;
  const bf16_t* vb = v + (long)bh * 2048 * 128;
  const float* bet = beta + (long)bh * 2048;
  const float* alp = alpha + (long)bh * 2048;
  const bf16_t* src = (tid < 128) ? (kb + tid) : (qb + (tid - 128));
  float* outb = out + (long)b * 2048 * 4096 + (long)h * 128 + dv;  // + t*4096

  float st[8] = {0, 0, 0, 0, 0, 0, 0, 0};
  __shared__ float kq[256];
  __shared__ float red[16][17];

  // depth-2 prefetch
  float kqA = (float)src[0];
  float vA = (float)vb[dv];
  float aA = alp[0], bA = bet[0];
  float kqB = (float)src[128];
  float vB = (float)vb[128 + dv];
  float aB = alp[1], bB = bet[1];

  for (int t = 0; t < 2048; ++t) {
    kq[tid] = kqA;
    __syncthreads();
    float kqC = 0.f, vC = 0.f, aC = 0.f, bC = 0.f;
    if (t + 2 < 2048) {
      long o = (long)(t + 2) * 128;
      kqC = (float)src[o];
      vC = (float)vb[o + dv];
      aC = alp[t + 2];
      bC = bet[t + 2];
    }
    float bv = bA * vA;
    float po = 0.f;
#pragma unroll
    for (int j = 0; j < 8; j++) {
      float kk = kq[g * 8 + j];
      float qq = kq[128 + g * 8 + j];
      st[j] = fmaf(aA, st[j], kk * bv);
      po = fmaf(qq, st[j], po);
    }
    red[g][dvi] = po;
    __syncthreads();
    if (tid < 16) {
      float s = 0.f;
#pragma unroll
      for (int gg = 0; gg < 16; gg++) s += red[gg][tid];
      outb[(long)t * 4096] = s;
    }
    kqA = kqB; vA = vB; aA = aB; bA = bB;
    kqB = kqC; vB = vC; aB = aC; bB = bC;
  }
}

// ---------------- RMS norm + gate(z) + cast -> A2 bf16 ----------------
// so: strided fp32 (row stride 4096). z read from qkvz columns 6144..8191.
__global__ __launch_bounds__(256) void k_rmsgate(const float* __restrict__ so,
                                                 const bf16_t* __restrict__ qkvz,
                                                 const float* __restrict__ norm_w,
                                                 bf16_t* __restrict__ A2) {
  int row = blockIdx.x;  // b*T + t
  int tid = threadIdx.x;
  int h = tid >> 4, j = tid & 15;
  const float* srow = so + (long)row * 4096 + h * 128 + j * 8;
  float xv[8];
  *(float4*)&xv[0] = *(const float4*)srow;
  *(float4*)&xv[4] = *(const float4*)(srow + 4);
  float ss = 0.f;
#pragma unroll
  for (int e = 0; e < 8; e++) ss += xv[e] * xv[e];
  ss += __shfl_xor(ss, 1); ss += __shfl_xor(ss, 2);
  ss += __shfl_xor(ss, 4); ss += __shfl_xor(ss, 8);
  float rinv = rsqrtf(ss * (1.0f / 128.0f) + 1e-6f);
  const bf16_t* zrow = qkvz + (long)row * 8192 + 6144 + h * 128 + j * 8;
  bf16x8 zv = *(const bf16x8*)zrow;
  bf16x8 o;
#pragma unroll
  for (int e = 0; e < 8; e++) {
    float z = (float)zv[e];
    float gate = 1.f / (1.f + expf(-z));
    o[e] = (bf16_t)(xv[e] * rinv * norm_w[j * 8 + e] * gate);
  }
  *(bf16x8*)(A2 + (long)row * 2048 + h * 128 + j * 8) = o;
}

extern "C" void kernel_launch(void* const* d_in, const int* in_sizes, int n_in,
                              void* d_out, int out_size, void* d_ws, size_t ws_size,
                              hipStream_t stream) {
  const float* x      = (const float*)d_in[0];
  // d_in[1] = positions (unused)
  const float* W_qkvz = (const float*)d_in[2];
  const float* W_b    = (const float*)d_in[3];
  const float* W_a    = (const float*)d_in[4];
  const float* conv_w = (const float*)d_in[5];
  const float* norm_w = (const float*)d_in[6];
  const float* W_out  = (const float*)d_in[7];
  float* out = (float*)d_out;
  char* ws = (char*)d_ws;

  // Aliased workspace layout, total 244,580,352 bytes (~245 MB).
  // Lifetimes: xb/WqT die after gemm1 -> reused as qv/kv (written by conv, after gemm1).
  //            vv dies after scan     -> reused as A2 (written by rmsgate, after scan).
  //            so (strided fp32, row stride 4096) aliases the qkv region of qkvz rows,
  //            which is dead after conv; z columns of qkvz remain live for rmsgate.
  //            d_out is written ONLY by the final GEMM (no mid-pipeline use).
  bf16_t* qkvz  = (bf16_t*)(ws + 0);           // 8192x8192 bf16 = 134,217,728 [gemm1 -> conv/rmsgate]
  bf16_t* xb    = (bf16_t*)(ws + 134217728);   // 8192x2048 bf16 = 33,554,432  [cast -> gemm1]
  bf16_t* qv    = (bf16_t*)(ws + 134217728);   // aliases xb      [conv -> scan]
  bf16_t* WqT   = (bf16_t*)(ws + 167772160);   // 8192x2048 bf16 = 33,554,432  [transpose -> gemm1]
  bf16_t* kv    = (bf16_t*)(ws + 167772160);   // aliases WqT     [conv -> scan]
  bf16_t* vv    = (bf16_t*)(ws + 201326592);   // 33,554,432      [conv -> scan]
  bf16_t* A2    = (bf16_t*)(ws + 201326592);   // aliases vv      [rmsgate -> gemm2]
  bf16_t* WoT   = (bf16_t*)(ws + 234881024);   // 2048x2048 bf16 = 8,388,608   [transpose -> gemm2]
  float*  WbT   = (float*)(ws + 243269632);    // 16x2048 f32 = 131,072
  float*  WaT   = (float*)(ws + 243400704);    // 131,072
  float*  beta  = (float*)(ws + 243531776);    // (B,H,T) f32 = 524,288
  float*  alpha = (float*)(ws + 244056064);    // 524,288
  float*  so    = (float*)qkvz;                 // strided: row r at so + r*4096 (bytes [0,8K) of each 16KB qkvz row)

  if (ws_size < 244580352) return;  // cannot run without scratch; avoid OOB faults

  k_cast_bf16<<<8192, 256, 0, stream>>>(x, xb);
  k_transpose_cast<<<dim3(8192 / 32, 2048 / 32), dim3(32, 8), 0, stream>>>(W_qkvz, WqT, 2048, 8192);
  k_transpose_cast<<<dim3(2048 / 32, 2048 / 32), dim3(32, 8), 0, stream>>>(W_out, WoT, 2048, 2048);
  k_transpose_f32<<<8, 256, 0, stream>>>(W_b, WbT, 2048, 16);
  k_transpose_f32<<<8, 256, 0, stream>>>(W_a, WaT, 2048, 16);
  k_beta_alpha<<<8192, 256, 0, stream>>>(x, WbT, WaT, beta, alpha);
  k_gemm_bt<bf16_t><<<dim3(64, 64), 256, 0, stream>>>(xb, WqT, qkvz, 8192, 8192, 2048);
  k_conv<<<8192, 256, 0, stream>>>(qkvz, conv_w, qv, kv, vv);
  k_scan<<<dim3(64, 8), 256, 0, stream>>>(qv, kv, vv, beta, alpha, so);
  k_rmsgate<<<8192, 256, 0, stream>>>(so, qkvz, norm_w, A2);
  k_gemm_bt<float><<<dim3(16, 64), 256, 0, stream>>>(A2, WoT, out, 8192, 2048, 2048);
  (void)in_sizes; (void)n_in; (void)out_size;
}

// Round 4
// 1224.844 us; speedup vs baseline: 1.7526x; 1.7526x over previous
//
#include <hip/hip_runtime.h>
#include <hip/hip_bf16.h>

typedef __bf16 bf16_t;
typedef __attribute__((ext_vector_type(8))) __bf16 bf16x8;
typedef __attribute__((ext_vector_type(4))) float floatx4;

// Problem constants: B=4, T=2048, C=2048, H=16, D=128, QKV_DIM=6144, QKVZ=8192, BT=8192

// ---------------- cast fp32 -> bf16 (vectorized) ----------------
__global__ __launch_bounds__(256) void k_cast_bf16(const float* __restrict__ in,
                                                   bf16_t* __restrict__ out) {
  long i = ((long)blockIdx.x * 256 + threadIdx.x) * 8;
  const float4 a = *(const float4*)(in + i);
  const float4 b = *(const float4*)(in + i + 4);
  bf16x8 o;
  o[0] = (bf16_t)a.x; o[1] = (bf16_t)a.y; o[2] = (bf16_t)a.z; o[3] = (bf16_t)a.w;
  o[4] = (bf16_t)b.x; o[5] = (bf16_t)b.y; o[6] = (bf16_t)b.z; o[7] = (bf16_t)b.w;
  *(bf16x8*)(out + i) = o;
}

// ---------------- transpose + cast fp32 -> bf16 ----------------
__global__ void k_transpose_cast(const float* __restrict__ in, bf16_t* __restrict__ out,
                                 int R, int Ccols) {
  __shared__ float tile[32][33];
  int c0 = blockIdx.x * 32, r0 = blockIdx.y * 32;
  for (int i = threadIdx.y; i < 32; i += 8)
    tile[i][threadIdx.x] = in[(long)(r0 + i) * Ccols + c0 + threadIdx.x];
  __syncthreads();
  for (int i = threadIdx.y; i < 32; i += 8)
    out[(long)(c0 + i) * R + r0 + threadIdx.x] = (bf16_t)tile[threadIdx.x][i];
}

// small fp32 transpose (for W_b / W_a: 2048x16 -> 16x2048)
__global__ void k_transpose_f32(const float* __restrict__ in, float* __restrict__ out,
                                int R, int Ccols) {
  int r = blockIdx.x * blockDim.x + threadIdx.x;
  if (r < R)
    for (int c = 0; c < Ccols; ++c) out[(long)c * R + r] = in[(long)r * Ccols + c];
}

// ---------------- beta/alpha: sigmoid(x @ W) ----------------
__global__ __launch_bounds__(256) void k_beta_alpha(const float* __restrict__ x,
                                                    const float* __restrict__ WbT,
                                                    const float* __restrict__ WaT,
                                                    float* __restrict__ beta,
                                                    float* __restrict__ alpha) {
  int row = blockIdx.x;  // b*T + t
  __shared__ float xs[2048];
  for (int i = threadIdx.x; i < 2048; i += 256) xs[i] = x[(long)row * 2048 + i];
  __syncthreads();
  int wave = threadIdx.x >> 6, lane = threadIdx.x & 63;
  for (int o = wave * 8; o < wave * 8 + 8; ++o) {
    const float* W = (o < 16) ? (WbT + (long)o * 2048) : (WaT + (long)(o - 16) * 2048);
    float s = 0.f;
    for (int k2 = lane; k2 < 2048; k2 += 64) s += xs[k2] * W[k2];
    for (int off = 32; off; off >>= 1) s += __shfl_down(s, off);
    if (lane == 0) {
      float sig = 1.f / (1.f + expf(-s));
      int b = row >> 11, t = row & 2047;
      int h = (o < 16) ? o : (o - 16);
      float* dst = (o < 16) ? beta : alpha;
      dst[((long)(b * 16 + h)) * 2048 + t] = sig;
    }
  }
}

// ---------------- bf16 MFMA GEMM: C = A @ Bt^T ----------------
template <typename OUT_T>
__global__ __launch_bounds__(256) void k_gemm_bt(const bf16_t* __restrict__ A,
                                                 const bf16_t* __restrict__ Bt,
                                                 OUT_T* __restrict__ C, int M, int N, int K) {
  constexpr int BK = 32;
  __shared__ alignas(16) bf16_t As[128][BK + 8];
  __shared__ alignas(16) bf16_t Bs[128][BK + 8];
  const int m0 = blockIdx.y * 128, n0 = blockIdx.x * 128;
  const int tid = threadIdx.x;
  const int wave = tid >> 6, lane = tid & 63;
  const int wr = wave >> 1, wc = wave & 1;
  const int lrow = lane & 15, lk = (lane >> 4) << 3;
  floatx4 acc[4][4] = {};
  const int srow = tid >> 2, scol = (tid & 3) * 8;
  const bf16_t* aptr = A + (long)(m0 + srow) * K + scol;
  const bf16_t* bptr = Bt + (long)(n0 + srow) * K + scol;
  const long half = 64 * (long)K;

  for (int k0 = 0; k0 < K; k0 += BK) {
    bf16x8 av0 = *(const bf16x8*)(aptr + k0);
    bf16x8 av1 = *(const bf16x8*)(aptr + half + k0);
    bf16x8 bv0 = *(const bf16x8*)(bptr + k0);
    bf16x8 bv1 = *(const bf16x8*)(bptr + half + k0);
    __syncthreads();
    *(bf16x8*)&As[srow][scol] = av0;
    *(bf16x8*)&As[srow + 64][scol] = av1;
    *(bf16x8*)&Bs[srow][scol] = bv0;
    *(bf16x8*)&Bs[srow + 64][scol] = bv1;
    __syncthreads();
    bf16x8 af[4], bfr[4];
#pragma unroll
    for (int i = 0; i < 4; i++) af[i] = *(const bf16x8*)&As[wr * 64 + i * 16 + lrow][lk];
#pragma unroll
    for (int i = 0; i < 4; i++) bfr[i] = *(const bf16x8*)&Bs[wc * 64 + i * 16 + lrow][lk];
#pragma unroll
    for (int mi = 0; mi < 4; mi++)
#pragma unroll
      for (int ni = 0; ni < 4; ni++)
        acc[mi][ni] = __builtin_amdgcn_mfma_f32_16x16x32_bf16(af[mi], bfr[ni], acc[mi][ni], 0, 0, 0);
  }
  const int crow_base = m0 + wr * 64 + (lane >> 4) * 4;
  const int ccol = n0 + wc * 64 + (lane & 15);
#pragma unroll
  for (int mi = 0; mi < 4; mi++)
#pragma unroll
    for (int ni = 0; ni < 4; ni++)
#pragma unroll
      for (int r = 0; r < 4; r++)
        C[(long)(crow_base + mi * 16 + r) * N + ccol + ni * 16] = (OUT_T)acc[mi][ni][r];
}

// ---------------- depthwise causal conv + SiLU + l2norm -> q,k,v ----------------
__global__ __launch_bounds__(256) void k_conv(const bf16_t* __restrict__ qkvz,
                                              const float* __restrict__ conv_w,
                                              bf16_t* __restrict__ q, bf16_t* __restrict__ k,
                                              bf16_t* __restrict__ v) {
  int row = blockIdx.x;  // b*T + t
  int b = row >> 11, t = row & 2047;
  __shared__ float ys[6144];
  __shared__ float gsum[32][9];
  __shared__ float norms[32];
  for (int c = threadIdx.x; c < 6144; c += 256) {
    float acc2 = 0.f;
#pragma unroll
    for (int w2 = 0; w2 < 4; ++w2) {
      int tt = t - 3 + w2;
      if (tt >= 0) acc2 += (float)qkvz[((long)(b * 2048 + tt)) * 8192 + c] * conv_w[c * 4 + w2];
    }
    ys[c] = acc2 / (1.f + expf(-acc2));  // silu
  }
  __syncthreads();
  {
    int g = threadIdx.x >> 3, j = threadIdx.x & 7;
    float s = 0.f;
#pragma unroll
    for (int e = 0; e < 16; ++e) {
      float yv = ys[g * 128 + j * 16 + e];
      s += yv * yv;
    }
    gsum[g][j] = s;
  }
  __syncthreads();
  if (threadIdx.x < 32) {
    float s = 0.f;
#pragma unroll
    for (int j = 0; j < 8; j++) s += gsum[threadIdx.x][j];
    norms[threadIdx.x] = 1.f / fmaxf(sqrtf(s), 1e-12f);
  }
  __syncthreads();
  for (int c = threadIdx.x; c < 6144; c += 256) {
    float yv = ys[c];
    if (c < 2048) {
      int h = c >> 7, d = c & 127;
      q[(((long)(b * 16 + h)) * 2048 + t) * 128 + d] = (bf16_t)(yv * norms[h]);
    } else if (c < 4096) {
      int cc = c - 2048, h = cc >> 7, d = cc & 127;
      k[(((long)(b * 16 + h)) * 2048 + t) * 128 + d] = (bf16_t)(yv * norms[16 + h]);
    } else {
      int cc = c - 4096, h = cc >> 7, d = cc & 127;
      v[(((long)(b * 16 + h)) * 2048 + t) * 128 + d] = (bf16_t)yv;
    }
  }
}

// ---------------- k,v natural -> kT,vT stripes inside dead qkvz region ----------------
// kT element (bh,dk,t) at qkvz elem (bh*128+dk)*8192 + 2048 + t   (bytes [4096,8192) of row)
// vT element (bh,dv,t) at qkvz elem (bh*128+dv)*8192 + 4096 + t   (bytes [8192,12288) of row)
__global__ __launch_bounds__(256) void k_tr_kv(const bf16_t* __restrict__ kv,
                                               const bf16_t* __restrict__ vv,
                                               bf16_t* __restrict__ qkvz) {
  __shared__ bf16_t t_lds[64 * 136];
  int bh = blockIdx.x >> 5, tc = blockIdx.x & 31;
  int t0 = tc * 64;
  int tid = threadIdx.x;
#pragma unroll
  for (int pass = 0; pass < 2; ++pass) {
    const bf16_t* src = (pass == 0 ? kv : vv) + (long)bh * 2048 * 128 + (long)t0 * 128;
    int r = tid >> 2, sc = (tid & 3) * 32;
    bf16x8 x0 = *(const bf16x8*)(src + (long)r * 128 + sc);
    bf16x8 x1 = *(const bf16x8*)(src + (long)r * 128 + sc + 8);
    bf16x8 x2 = *(const bf16x8*)(src + (long)r * 128 + sc + 16);
    bf16x8 x3 = *(const bf16x8*)(src + (long)r * 128 + sc + 24);
    __syncthreads();  // protect LDS from previous pass readers
    *(bf16x8*)&t_lds[r * 136 + sc] = x0;
    *(bf16x8*)&t_lds[r * 136 + sc + 8] = x1;
    *(bf16x8*)&t_lds[r * 136 + sc + 16] = x2;
    *(bf16x8*)&t_lds[r * 136 + sc + 24] = x3;
    __syncthreads();
    int d = tid >> 1, h2 = tid & 1;
    bf16_t* dst = qkvz + (long)(bh * 128 + d) * 8192 + (pass ? 4096 : 2048) + t0 + h2 * 32;
#pragma unroll
    for (int g = 0; g < 4; ++g) {
      bf16x8 o;
#pragma unroll
      for (int j = 0; j < 8; ++j) o[j] = t_lds[(h2 * 32 + g * 8 + j) * 136 + d];
      *(bf16x8*)(dst + g * 8) = o;
    }
  }
}

// ---------------- fused chunked gated-linear-attention scan + RMS/gate epilogue ----------
// Grid: 64 blocks (bh), 512 threads (8 waves). Chunk Tc=64, 32 chunks sequential.
// State S^T[dv][dk] master in fp32 registers (wave w owns dv rows w*16..w*16+15),
// bf16 mirror in LDS for the inter GEMM's B-operand.
__global__ __launch_bounds__(512, 1) void k_scan_chunked(
    const bf16_t* __restrict__ qv, const bf16_t* __restrict__ kv,
    const bf16_t* __restrict__ qkvz,  // kT/vT stripes + z region
    const float* __restrict__ beta, const float* __restrict__ alpha,
    const float* __restrict__ norm_w, bf16_t* __restrict__ A2) {
  extern __shared__ char smem[];
  bf16_t* q_lds = (bf16_t*)smem;            // [64][136]
  bf16_t* kn_lds = q_lds + 8704;            // [64][136]
  bf16_t* kT_lds = kn_lds + 8704;           // [128][72] (scaled in place -> K')
  bf16_t* vT_lds = kT_lds + 9216;           // [128][72]
  bf16_t* P_lds = vT_lds + 9216;            // [64][72]
  bf16_t* St_lds = P_lds + 4608;            // [128][136] bf16 state mirror
  float* G_lds = (float*)(St_lds + 17408);  // [64]
  float* bet_lds = G_lds + 64;              // [64]
  float* w_lds = bet_lds + 64;              // [64] beta_s * exp(Gend - G_s)
  float* eG_lds = w_lds + 64;               // [64] exp(G_t)
  float* rms_lds = eG_lds + 64;             // [64][9]

  const int bh = blockIdx.x;
  const int b = bh >> 4, h = bh & 15;
  const int tid = threadIdx.x;
  const int w = tid >> 6, l = tid & 63;
  const int l15 = l & 15, lg = l >> 4;

  const bf16_t* qb = qv + (long)bh * 2048 * 128;
  const bf16_t* kb = kv + (long)bh * 2048 * 128;
  const bf16_t* kTg = qkvz + (long)bh * 128 * 8192 + 2048;  // +dk*8192 + t ; vT at +2048
  const float* bet = beta + (long)bh * 2048;
  const float* alp = alpha + (long)bh * 2048;
  const float nwl = norm_w[w * 16 + l15];

  floatx4 streg[8];
#pragma unroll
  for (int i = 0; i < 8; i++) streg[i] = (floatx4){0.f, 0.f, 0.f, 0.f};
  for (int i = tid; i < 8704; i += 512) ((float*)St_lds)[i] = 0.f;
  __syncthreads();

  // staging coords
  const int sr = tid >> 3, ssc = (tid & 7) * 16;   // q/kn: 64 x 128
  const int sdk = tid >> 2, ssc2 = (tid & 3) * 16; // kT/vT: 128 x 64

  for (int c = 0; c < 32; ++c) {
    const int t0 = c * 64;
    // ---- phase A: stage tiles + (wave0) decay math ----
    {
      const bf16_t* qs = qb + (long)(t0 + sr) * 128 + ssc;
      const bf16_t* ks = kb + (long)(t0 + sr) * 128 + ssc;
      const bf16_t* kts = kTg + (long)sdk * 8192 + t0 + ssc2;
      bf16x8 a0 = *(const bf16x8*)qs, a1 = *(const bf16x8*)(qs + 8);
      bf16x8 b0 = *(const bf16x8*)ks, b1 = *(const bf16x8*)(ks + 8);
      bf16x8 c0 = *(const bf16x8*)kts, c1 = *(const bf16x8*)(kts + 8);
      bf16x8 d0 = *(const bf16x8*)(kts + 2048), d1 = *(const bf16x8*)(kts + 2056);
      *(bf16x8*)&q_lds[sr * 136 + ssc] = a0;
      *(bf16x8*)&q_lds[sr * 136 + ssc + 8] = a1;
      *(bf16x8*)&kn_lds[sr * 136 + ssc] = b0;
      *(bf16x8*)&kn_lds[sr * 136 + ssc + 8] = b1;
      *(bf16x8*)&kT_lds[sdk * 72 + ssc2] = c0;
      *(bf16x8*)&kT_lds[sdk * 72 + ssc2 + 8] = c1;
      *(bf16x8*)&vT_lds[sdk * 72 + ssc2] = d0;
      *(bf16x8*)&vT_lds[sdk * 72 + ssc2 + 8] = d1;
      if (w == 0) {
        float bsv = bet[t0 + l];
        float la = __logf(alp[t0 + l]);
#pragma unroll
        for (int off = 1; off < 64; off <<= 1) {
          float xup = __shfl_up(la, off);
          if (l >= off) la += xup;
        }
        float ge = __shfl(la, 63);
        G_lds[l] = la;
        bet_lds[l] = bsv;
        w_lds[l] = bsv * __expf(ge - la);
        eG_lds[l] = __expf(la);
      }
    }
    __syncthreads();  // b1

    // ---- phase B: scale kT in place -> K'[dk][s] = k[s][dk]*beta_s*exp(Gend-G_s) ----
    {
      bf16_t* p = &kT_lds[sdk * 72 + ssc2];
      bf16x8 x0 = *(bf16x8*)p, x1 = *(bf16x8*)(p + 8);
#pragma unroll
      for (int j = 0; j < 8; j++) {
        x0[j] = (bf16_t)((float)x0[j] * w_lds[ssc2 + j]);
        x1[j] = (bf16_t)((float)x1[j] * w_lds[ssc2 + 8 + j]);
      }
      *(bf16x8*)p = x0;
      *(bf16x8*)(p + 8) = x1;
    }

    // ---- phase CD: score = q K^T (2 tiles/wave), build P ----
    {
      const int mi = w >> 1;
      bf16x8 aq[4];
#pragma unroll
      for (int ks = 0; ks < 4; ks++)
        aq[ks] = *(bf16x8*)&q_lds[(mi * 16 + l15) * 136 + ks * 32 + lg * 8];
#pragma unroll
      for (int sn2 = 0; sn2 < 2; sn2++) {
        const int sn = (w & 1) * 2 + sn2;
        floatx4 sc_ = {0.f, 0.f, 0.f, 0.f};
#pragma unroll
        for (int ks = 0; ks < 4; ks++) {
          bf16x8 bk = *(bf16x8*)&kn_lds[(sn * 16 + l15) * 136 + ks * 32 + lg * 8];
          sc_ = __builtin_amdgcn_mfma_f32_16x16x32_bf16(aq[ks], bk, sc_, 0, 0, 0);
        }
        const int sl = sn * 16 + l15;
        const float gs = G_lds[sl], bs = bet_lds[sl];
#pragma unroll
        for (int r = 0; r < 4; r++) {
          const int tl = mi * 16 + lg * 4 + r;
          float val = (sl <= tl) ? sc_[r] * __expf(G_lds[tl] - gs) * bs : 0.f;
          P_lds[tl * 72 + sl] = (bf16_t)val;
        }
      }
    }
    __syncthreads();  // b3

    // ---- phase E: out = exp(Gt)*(q @ S_in) + P @ V ; state update ----
    floatx4 accout[4];
    {
      const int rA = w * 16 + l15;  // dv row this wave owns (cols of out)
      bf16x8 av0 = *(bf16x8*)&vT_lds[rA * 72 + lg * 8];
      bf16x8 av1 = *(bf16x8*)&vT_lds[rA * 72 + 32 + lg * 8];
#pragma unroll
      for (int mi = 0; mi < 4; mi++) {
        floatx4 f = {0.f, 0.f, 0.f, 0.f};
#pragma unroll
        for (int ks = 0; ks < 4; ks++) {
          bf16x8 aq = *(bf16x8*)&q_lds[(mi * 16 + l15) * 136 + ks * 32 + lg * 8];
          bf16x8 bs_ = *(bf16x8*)&St_lds[rA * 136 + ks * 32 + lg * 8];
          f = __builtin_amdgcn_mfma_f32_16x16x32_bf16(aq, bs_, f, 0, 0, 0);
        }
#pragma unroll
        for (int r = 0; r < 4; r++) f[r] *= eG_lds[mi * 16 + lg * 4 + r];
#pragma unroll
        for (int ks2 = 0; ks2 < 2; ks2++) {
          bf16x8 ap = *(bf16x8*)&P_lds[(mi * 16 + l15) * 72 + ks2 * 32 + lg * 8];
          f = __builtin_amdgcn_mfma_f32_16x16x32_bf16(ap, (ks2 == 0) ? av0 : av1, f, 0, 0, 0);
        }
        accout[mi] = f;
      }
      const float dcv = eG_lds[63];
#pragma unroll
      for (int ni2 = 0; ni2 < 8; ni2++) {
#pragma unroll
        for (int r = 0; r < 4; r++) streg[ni2][r] *= dcv;
        bf16x8 bk0 = *(bf16x8*)&kT_lds[(ni2 * 16 + l15) * 72 + lg * 8];
        bf16x8 bk1 = *(bf16x8*)&kT_lds[(ni2 * 16 + l15) * 72 + 32 + lg * 8];
        streg[ni2] = __builtin_amdgcn_mfma_f32_16x16x32_bf16(av0, bk0, streg[ni2], 0, 0, 0);
        streg[ni2] = __builtin_amdgcn_mfma_f32_16x16x32_bf16(av1, bk1, streg[ni2], 0, 0, 0);
      }
    }
    __syncthreads();  // b4 (inter reads of St_lds complete)

    // ---- phase F: publish new state, RMS reduce, gated write ----
#pragma unroll
    for (int ni2 = 0; ni2 < 8; ni2++)
#pragma unroll
      for (int r = 0; r < 4; r++)
        St_lds[(w * 16 + lg * 4 + r) * 136 + ni2 * 16 + l15] = (bf16_t)streg[ni2][r];
#pragma unroll
    for (int mi = 0; mi < 4; mi++)
#pragma unroll
      for (int r = 0; r < 4; r++) {
        float v2 = accout[mi][r] * accout[mi][r];
        v2 += __shfl_xor(v2, 1);
        v2 += __shfl_xor(v2, 2);
        v2 += __shfl_xor(v2, 4);
        v2 += __shfl_xor(v2, 8);
        if (l15 == 0) rms_lds[(mi * 16 + lg * 4 + r) * 9 + w] = v2;
      }
    __syncthreads();  // b5
    if (tid < 64) {
      float tot = 0.f;
#pragma unroll
      for (int w2 = 0; w2 < 8; w2++) tot += rms_lds[tid * 9 + w2];
      rms_lds[tid * 9 + 8] = rsqrtf(tot * (1.f / 128.f) + 1e-6f);
    }
    __syncthreads();  // b6
    {
      const bf16_t* zrow = qkvz + (long)(b * 2048 + t0) * 8192 + 6144 + h * 128 + w * 16 + l15;
      bf16_t* arow = A2 + (long)(b * 2048 + t0) * 2048 + h * 128 + w * 16 + l15;
#pragma unroll
      for (int mi = 0; mi < 4; mi++)
#pragma unroll
        for (int r = 0; r < 4; r++) {
          const int tl = mi * 16 + lg * 4 + r;
          float z = (float)zrow[(long)tl * 8192];
          float gate = 1.f / (1.f + __expf(-z));
          arow[(long)tl * 2048] = (bf16_t)(accout[mi][r] * rms_lds[tl * 9 + 8] * nwl * gate);
        }
    }
    // no barrier needed: next phase A writes tiles not read here; b1 orders everything else
  }
}

extern "C" void kernel_launch(void* const* d_in, const int* in_sizes, int n_in,
                              void* d_out, int out_size, void* d_ws, size_t ws_size,
                              hipStream_t stream) {
  const float* x      = (const float*)d_in[0];
  // d_in[1] = positions (unused)
  const float* W_qkvz = (const float*)d_in[2];
  const float* W_b    = (const float*)d_in[3];
  const float* W_a    = (const float*)d_in[4];
  const float* conv_w = (const float*)d_in[5];
  const float* norm_w = (const float*)d_in[6];
  const float* W_out  = (const float*)d_in[7];
  float* out = (float*)d_out;
  char* ws = (char*)d_ws;

  // Workspace layout identical to the passing round (244,580,352 bytes).
  // qkvz row (16 KB): [0,4K) dead, [4K,8K) kT stripes, [8K,12K) vT stripes, [12K,16K) z (live).
  bf16_t* qkvz  = (bf16_t*)(ws + 0);           // 8192x8192 bf16 [gemm1 -> conv/tr/scan]
  bf16_t* xb    = (bf16_t*)(ws + 134217728);   // [cast -> gemm1]
  bf16_t* qv    = (bf16_t*)(ws + 134217728);   // aliases xb [conv -> scan]
  bf16_t* WqT   = (bf16_t*)(ws + 167772160);   // [transpose -> gemm1]
  bf16_t* kv    = (bf16_t*)(ws + 167772160);   // aliases WqT [conv -> scan]
  bf16_t* vv    = (bf16_t*)(ws + 201326592);   // [conv -> tr_kv]
  bf16_t* A2    = (bf16_t*)(ws + 201326592);   // aliases vv [scan -> gemm2]
  bf16_t* WoT   = (bf16_t*)(ws + 234881024);   // [transpose -> gemm2]
  float*  WbT   = (float*)(ws + 243269632);
  float*  WaT   = (float*)(ws + 243400704);
  float*  beta  = (float*)(ws + 243531776);
  float*  alpha = (float*)(ws + 244056064);

  if (ws_size < 244580352) return;

  k_cast_bf16<<<8192, 256, 0, stream>>>(x, xb);
  k_transpose_cast<<<dim3(8192 / 32, 2048 / 32), dim3(32, 8), 0, stream>>>(W_qkvz, WqT, 2048, 8192);
  k_transpose_cast<<<dim3(2048 / 32, 2048 / 32), dim3(32, 8), 0, stream>>>(W_out, WoT, 2048, 2048);
  k_transpose_f32<<<8, 256, 0, stream>>>(W_b, WbT, 2048, 16);
  k_transpose_f32<<<8, 256, 0, stream>>>(W_a, WaT, 2048, 16);
  k_beta_alpha<<<8192, 256, 0, stream>>>(x, WbT, WaT, beta, alpha);
  k_gemm_bt<bf16_t><<<dim3(64, 64), 256, 0, stream>>>(xb, WqT, qkvz, 8192, 8192, 2048);
  k_conv<<<8192, 256, 0, stream>>>(qkvz, conv_w, qv, kv, vv);
  k_tr_kv<<<2048, 256, 0, stream>>>(kv, vv, qkvz);
  k_scan_chunked<<<64, 512, 119040, stream>>>(qv, kv, qkvz, beta, alpha, norm_w, A2);
  k_gemm_bt<float><<<dim3(16, 64), 256, 0, stream>>>(A2, WoT, out, 8192, 2048, 2048);
  (void)in_sizes; (void)n_in; (void)out_size;
}

// Round 5
// 1100.474 us; speedup vs baseline: 1.9507x; 1.1130x over previous
//
#include <hip/hip_runtime.h>
#include <hip/hip_bf16.h>

typedef __bf16 bf16_t;
typedef __attribute__((ext_vector_type(8))) __bf16 bf16x8;
typedef __attribute__((ext_vector_type(4))) float floatx4;

// Problem constants: B=4, T=2048, C=2048, H=16, D=128, QKV_DIM=6144, QKVZ=8192, BT=8192

__device__ __forceinline__ void gload16(const void* g, void* l) {
  __builtin_amdgcn_global_load_lds(
      (const __attribute__((address_space(1))) void*)g,
      (__attribute__((address_space(3))) void*)l, 16, 0, 0);
}

// ---------------- cast fp32 -> bf16 (vectorized) ----------------
__global__ __launch_bounds__(256) void k_cast_bf16(const float* __restrict__ in,
                                                   bf16_t* __restrict__ out) {
  long i = ((long)blockIdx.x * 256 + threadIdx.x) * 8;
  const float4 a = *(const float4*)(in + i);
  const float4 b = *(const float4*)(in + i + 4);
  bf16x8 o;
  o[0] = (bf16_t)a.x; o[1] = (bf16_t)a.y; o[2] = (bf16_t)a.z; o[3] = (bf16_t)a.w;
  o[4] = (bf16_t)b.x; o[5] = (bf16_t)b.y; o[6] = (bf16_t)b.z; o[7] = (bf16_t)b.w;
  *(bf16x8*)(out + i) = o;
}

// ---------------- transpose + cast fp32 -> bf16 ----------------
__global__ void k_transpose_cast(const float* __restrict__ in, bf16_t* __restrict__ out,
                                 int R, int Ccols) {
  __shared__ float tile[32][33];
  int c0 = blockIdx.x * 32, r0 = blockIdx.y * 32;
  for (int i = threadIdx.y; i < 32; i += 8)
    tile[i][threadIdx.x] = in[(long)(r0 + i) * Ccols + c0 + threadIdx.x];
  __syncthreads();
  for (int i = threadIdx.y; i < 32; i += 8)
    out[(long)(c0 + i) * R + r0 + threadIdx.x] = (bf16_t)tile[threadIdx.x][i];
}

// small fp32 transpose (for W_b / W_a: 2048x16 -> 16x2048)
__global__ void k_transpose_f32(const float* __restrict__ in, float* __restrict__ out,
                                int R, int Ccols) {
  int r = blockIdx.x * blockDim.x + threadIdx.x;
  if (r < R)
    for (int c = 0; c < Ccols; ++c) out[(long)c * R + r] = in[(long)r * Ccols + c];
}

// ---------------- beta/alpha: sigmoid(x @ W) ----------------
__global__ __launch_bounds__(256) void k_beta_alpha(const float* __restrict__ x,
                                                    const float* __restrict__ WbT,
                                                    const float* __restrict__ WaT,
                                                    float* __restrict__ beta,
                                                    float* __restrict__ alpha) {
  int row = blockIdx.x;  // b*T + t
  __shared__ float xs[2048];
  for (int i = threadIdx.x; i < 2048; i += 256) xs[i] = x[(long)row * 2048 + i];
  __syncthreads();
  int wave = threadIdx.x >> 6, lane = threadIdx.x & 63;
  for (int o = wave * 8; o < wave * 8 + 8; ++o) {
    const float* W = (o < 16) ? (WbT + (long)o * 2048) : (WaT + (long)(o - 16) * 2048);
    float s = 0.f;
    for (int k2 = lane; k2 < 2048; k2 += 64) s += xs[k2] * W[k2];
    for (int off = 32; off; off >>= 1) s += __shfl_down(s, off);
    if (lane == 0) {
      float sig = 1.f / (1.f + expf(-s));
      int b = row >> 11, t = row & 2047;
      int h = (o < 16) ? o : (o - 16);
      float* dst = (o < 16) ? beta : alpha;
      dst[((long)(b * 16 + h)) * 2048 + t] = sig;
    }
  }
}

// ---------------- bf16 MFMA GEMM: C = A @ Bt^T (m97 structure) ----------------
// A: M x K row-major bf16. Bt: N x K row-major bf16. C: M x N row-major OUT_T.
// BM=BN=128, BK=32; 256 threads (4 waves, 2x2), wave tile 64x64 via 4x4 16x16x32 frags.
// Staging via global_load_lds width=16: LDS linear [128][32] (64 B/row); wave w stages
// rows [w*32, w*32+32) of each tile (2 issues x 1 KiB/wave/tile). Lane mapping check:
// lane*16 bytes == (lane>>2)*64 + (lane&3)*16  -> row w*32+j*16+(lane>>2), col (lane&3)*8.
template <typename OUT_T>
__global__ __launch_bounds__(256) void k_gemm_bt(const bf16_t* __restrict__ A,
                                                 const bf16_t* __restrict__ Bt,
                                                 OUT_T* __restrict__ C, int M, int N, int K) {
  constexpr int BK = 32;
  __shared__ alignas(16) bf16_t As[128 * BK];
  __shared__ alignas(16) bf16_t Bs[128 * BK];
  const int m0 = blockIdx.y * 128, n0 = blockIdx.x * 128;
  const int tid = threadIdx.x;
  const int wave = tid >> 6, lane = tid & 63;
  const int wr = wave >> 1, wc = wave & 1;
  const int lrow = lane & 15, lk = (lane >> 4) << 3;
  floatx4 acc[4][4] = {};

  const int srow0 = wave * 32 + (lane >> 2);
  const int scol = (lane & 3) * 8;
  const bf16_t* aptr = A + (long)(m0 + srow0) * K + scol;
  const bf16_t* bptr = Bt + (long)(n0 + srow0) * K + scol;
  const long rstep = 16 * (long)K;
  bf16_t* as0 = &As[(wave * 32) * BK];
  bf16_t* as1 = &As[(wave * 32 + 16) * BK];
  bf16_t* bs0 = &Bs[(wave * 32) * BK];
  bf16_t* bs1 = &Bs[(wave * 32 + 16) * BK];

  for (int k0 = 0; k0 < K; k0 += BK) {
    __syncthreads();  // all waves done reading previous tile
    gload16(aptr + k0, as0);
    gload16(aptr + rstep + k0, as1);
    gload16(bptr + k0, bs0);
    gload16(bptr + rstep + k0, bs1);
    __syncthreads();  // compiler emits vmcnt(0) drain before s_barrier -> data visible
    bf16x8 af[4], bfr[4];
#pragma unroll
    for (int i = 0; i < 4; i++) af[i] = *(const bf16x8*)&As[(wr * 64 + i * 16 + lrow) * BK + lk];
#pragma unroll
    for (int i = 0; i < 4; i++) bfr[i] = *(const bf16x8*)&Bs[(wc * 64 + i * 16 + lrow) * BK + lk];
#pragma unroll
    for (int mi = 0; mi < 4; mi++)
#pragma unroll
      for (int ni = 0; ni < 4; ni++)
        acc[mi][ni] = __builtin_amdgcn_mfma_f32_16x16x32_bf16(af[mi], bfr[ni], acc[mi][ni], 0, 0, 0);
  }
  const int crow_base = m0 + wr * 64 + (lane >> 4) * 4;
  const int ccol = n0 + wc * 64 + (lane & 15);
#pragma unroll
  for (int mi = 0; mi < 4; mi++)
#pragma unroll
    for (int ni = 0; ni < 4; ni++)
#pragma unroll
      for (int r = 0; r < 4; r++)
        C[(long)(crow_base + mi * 16 + r) * N + ccol + ni * 16] = (OUT_T)acc[mi][ni][r];
}

// ---------------- depthwise causal conv + SiLU + l2norm -> q,k,v (vectorized) ---------
__global__ __launch_bounds__(256) void k_conv(const bf16_t* __restrict__ qkvz,
                                              const float* __restrict__ conv_w,
                                              bf16_t* __restrict__ q, bf16_t* __restrict__ k,
                                              bf16_t* __restrict__ v) {
  int row = blockIdx.x;  // b*T + t
  int b = row >> 11, t = row & 2047;
  __shared__ float ys[6144];
  __shared__ float gsum[32][9];
  __shared__ float norms[32];
  const int c0 = threadIdx.x * 8;
  for (int c8 = c0; c8 < 6144; c8 += 2048) {
    bf16x8 xr[4];
#pragma unroll
    for (int w2 = 0; w2 < 4; ++w2) {
      int tt = t - 3 + w2;
      bf16x8 zr = {};
      xr[w2] = (tt >= 0) ? *(const bf16x8*)&qkvz[((long)(b * 2048 + tt)) * 8192 + c8] : zr;
    }
#pragma unroll
    for (int j = 0; j < 8; ++j) {
      float4 wv = *(const float4*)&conv_w[(c8 + j) * 4];
      float a = (float)xr[0][j] * wv.x + (float)xr[1][j] * wv.y +
                (float)xr[2][j] * wv.z + (float)xr[3][j] * wv.w;
      ys[c8 + j] = a / (1.f + __expf(-a));  // silu
    }
  }
  __syncthreads();
  {
    int g = threadIdx.x >> 3, j = threadIdx.x & 7;
    float s = 0.f;
#pragma unroll
    for (int e = 0; e < 16; ++e) {
      float yv = ys[g * 128 + j * 16 + e];
      s += yv * yv;
    }
    gsum[g][j] = s;
  }
  __syncthreads();
  if (threadIdx.x < 32) {
    float s = 0.f;
#pragma unroll
    for (int j = 0; j < 8; j++) s += gsum[threadIdx.x][j];
    norms[threadIdx.x] = 1.f / fmaxf(sqrtf(s), 1e-12f);
  }
  __syncthreads();
  for (int c8 = c0; c8 < 6144; c8 += 2048) {
    float scale;
    bf16_t* dst;
    if (c8 < 2048) {
      int h = c8 >> 7;
      scale = norms[h];
      dst = q + (((long)(b * 16 + h)) * 2048 + t) * 128 + (c8 & 127);
    } else if (c8 < 4096) {
      int h = (c8 - 2048) >> 7;
      scale = norms[16 + h];
      dst = k + (((long)(b * 16 + h)) * 2048 + t) * 128 + (c8 & 127);
    } else {
      scale = 1.f;
      int h = (c8 - 4096) >> 7;
      dst = v + (((long)(b * 16 + h)) * 2048 + t) * 128 + (c8 & 127);
    }
    bf16x8 o;
#pragma unroll
    for (int j = 0; j < 8; ++j) o[j] = (bf16_t)(ys[c8 + j] * scale);
    *(bf16x8*)dst = o;
  }
}

// ---------------- k,v natural -> kT,vT stripes inside dead qkvz region ----------------
__global__ __launch_bounds__(256) void k_tr_kv(const bf16_t* __restrict__ kv,
                                               const bf16_t* __restrict__ vv,
                                               bf16_t* __restrict__ qkvz) {
  __shared__ bf16_t t_lds[64 * 136];
  int bh = blockIdx.x >> 5, tc = blockIdx.x & 31;
  int t0 = tc * 64;
  int tid = threadIdx.x;
#pragma unroll
  for (int pass = 0; pass < 2; ++pass) {
    const bf16_t* src = (pass == 0 ? kv : vv) + (long)bh * 2048 * 128 + (long)t0 * 128;
    int r = tid >> 2, sc = (tid & 3) * 32;
    bf16x8 x0 = *(const bf16x8*)(src + (long)r * 128 + sc);
    bf16x8 x1 = *(const bf16x8*)(src + (long)r * 128 + sc + 8);
    bf16x8 x2 = *(const bf16x8*)(src + (long)r * 128 + sc + 16);
    bf16x8 x3 = *(const bf16x8*)(src + (long)r * 128 + sc + 24);
    __syncthreads();
    *(bf16x8*)&t_lds[r * 136 + sc] = x0;
    *(bf16x8*)&t_lds[r * 136 + sc + 8] = x1;
    *(bf16x8*)&t_lds[r * 136 + sc + 16] = x2;
    *(bf16x8*)&t_lds[r * 136 + sc + 24] = x3;
    __syncthreads();
    int d = tid >> 1, h2 = tid & 1;
    bf16_t* dst = qkvz + (long)(bh * 128 + d) * 8192 + (pass ? 4096 : 2048) + t0 + h2 * 32;
#pragma unroll
    for (int g = 0; g < 4; ++g) {
      bf16x8 o;
#pragma unroll
      for (int j = 0; j < 8; ++j) o[j] = t_lds[(h2 * 32 + g * 8 + j) * 136 + d];
      *(bf16x8*)(dst + g * 8) = o;
    }
  }
}

// ---------------- fused chunked gated-linear-attention scan + RMS/gate epilogue ----------
__global__ __launch_bounds__(512, 1) void k_scan_chunked(
    const bf16_t* __restrict__ qv, const bf16_t* __restrict__ kv,
    const bf16_t* __restrict__ qkvz,  // kT/vT stripes + z region
    const float* __restrict__ beta, const float* __restrict__ alpha,
    const float* __restrict__ norm_w, bf16_t* __restrict__ A2) {
  extern __shared__ char smem[];
  bf16_t* q_lds = (bf16_t*)smem;            // [64][136]
  bf16_t* kn_lds = q_lds + 8704;            // [64][136]
  bf16_t* kT_lds = kn_lds + 8704;           // [128][72]
  bf16_t* vT_lds = kT_lds + 9216;           // [128][72]
  bf16_t* P_lds = vT_lds + 9216;            // [64][72]
  bf16_t* St_lds = P_lds + 4608;            // [128][136]
  float* G_lds = (float*)(St_lds + 17408);  // [64]
  float* bet_lds = G_lds + 64;
  float* w_lds = bet_lds + 64;
  float* eG_lds = w_lds + 64;
  float* rms_lds = eG_lds + 64;             // [64][9]

  const int bh = blockIdx.x;
  const int b = bh >> 4, h = bh & 15;
  const int tid = threadIdx.x;
  const int w = tid >> 6, l = tid & 63;
  const int l15 = l & 15, lg = l >> 4;

  const bf16_t* qb = qv + (long)bh * 2048 * 128;
  const bf16_t* kb = kv + (long)bh * 2048 * 128;
  const bf16_t* kTg = qkvz + (long)bh * 128 * 8192 + 2048;
  const float* bet = beta + (long)bh * 2048;
  const float* alp = alpha + (long)bh * 2048;
  const float nwl = norm_w[w * 16 + l15];

  floatx4 streg[8];
#pragma unroll
  for (int i = 0; i < 8; i++) streg[i] = (floatx4){0.f, 0.f, 0.f, 0.f};
  for (int i = tid; i < 8704; i += 512) ((float*)St_lds)[i] = 0.f;
  __syncthreads();

  const int sr = tid >> 3, ssc = (tid & 7) * 16;
  const int sdk = tid >> 2, ssc2 = (tid & 3) * 16;

  for (int c = 0; c < 32; ++c) {
    const int t0 = c * 64;
    {
      const bf16_t* qs = qb + (long)(t0 + sr) * 128 + ssc;
      const bf16_t* ks = kb + (long)(t0 + sr) * 128 + ssc;
      const bf16_t* kts = kTg + (long)sdk * 8192 + t0 + ssc2;
      bf16x8 a0 = *(const bf16x8*)qs, a1 = *(const bf16x8*)(qs + 8);
      bf16x8 b0 = *(const bf16x8*)ks, b1 = *(const bf16x8*)(ks + 8);
      bf16x8 c0 = *(const bf16x8*)kts, c1 = *(const bf16x8*)(kts + 8);
      bf16x8 d0 = *(const bf16x8*)(kts + 2048), d1 = *(const bf16x8*)(kts + 2056);
      *(bf16x8*)&q_lds[sr * 136 + ssc] = a0;
      *(bf16x8*)&q_lds[sr * 136 + ssc + 8] = a1;
      *(bf16x8*)&kn_lds[sr * 136 + ssc] = b0;
      *(bf16x8*)&kn_lds[sr * 136 + ssc + 8] = b1;
      *(bf16x8*)&kT_lds[sdk * 72 + ssc2] = c0;
      *(bf16x8*)&kT_lds[sdk * 72 + ssc2 + 8] = c1;
      *(bf16x8*)&vT_lds[sdk * 72 + ssc2] = d0;
      *(bf16x8*)&vT_lds[sdk * 72 + ssc2 + 8] = d1;
      if (w == 0) {
        float bsv = bet[t0 + l];
        float la = __logf(alp[t0 + l]);
#pragma unroll
        for (int off = 1; off < 64; off <<= 1) {
          float xup = __shfl_up(la, off);
          if (l >= off) la += xup;
        }
        float ge = __shfl(la, 63);
        G_lds[l] = la;
        bet_lds[l] = bsv;
        w_lds[l] = bsv * __expf(ge - la);
        eG_lds[l] = __expf(la);
      }
    }
    __syncthreads();

    {
      bf16_t* p = &kT_lds[sdk * 72 + ssc2];
      bf16x8 x0 = *(bf16x8*)p, x1 = *(bf16x8*)(p + 8);
#pragma unroll
      for (int j = 0; j < 8; j++) {
        x0[j] = (bf16_t)((float)x0[j] * w_lds[ssc2 + j]);
        x1[j] = (bf16_t)((float)x1[j] * w_lds[ssc2 + 8 + j]);
      }
      *(bf16x8*)p = x0;
      *(bf16x8*)(p + 8) = x1;
    }

    {
      const int mi = w >> 1;
      bf16x8 aq[4];
#pragma unroll
      for (int ks = 0; ks < 4; ks++)
        aq[ks] = *(bf16x8*)&q_lds[(mi * 16 + l15) * 136 + ks * 32 + lg * 8];
#pragma unroll
      for (int sn2 = 0; sn2 < 2; sn2++) {
        const int sn = (w & 1) * 2 + sn2;
        floatx4 sc_ = {0.f, 0.f, 0.f, 0.f};
#pragma unroll
        for (int ks = 0; ks < 4; ks++) {
          bf16x8 bk = *(bf16x8*)&kn_lds[(sn * 16 + l15) * 136 + ks * 32 + lg * 8];
          sc_ = __builtin_amdgcn_mfma_f32_16x16x32_bf16(aq[ks], bk, sc_, 0, 0, 0);
        }
        const int sl = sn * 16 + l15;
        const float gs = G_lds[sl], bs = bet_lds[sl];
#pragma unroll
        for (int r = 0; r < 4; r++) {
          const int tl = mi * 16 + lg * 4 + r;
          float val = (sl <= tl) ? sc_[r] * __expf(G_lds[tl] - gs) * bs : 0.f;
          P_lds[tl * 72 + sl] = (bf16_t)val;
        }
      }
    }
    __syncthreads();

    floatx4 accout[4];
    {
      const int rA = w * 16 + l15;
      bf16x8 av0 = *(bf16x8*)&vT_lds[rA * 72 + lg * 8];
      bf16x8 av1 = *(bf16x8*)&vT_lds[rA * 72 + 32 + lg * 8];
#pragma unroll
      for (int mi = 0; mi < 4; mi++) {
        floatx4 f = {0.f, 0.f, 0.f, 0.f};
#pragma unroll
        for (int ks = 0; ks < 4; ks++) {
          bf16x8 aq = *(bf16x8*)&q_lds[(mi * 16 + l15) * 136 + ks * 32 + lg * 8];
          bf16x8 bs_ = *(bf16x8*)&St_lds[rA * 136 + ks * 32 + lg * 8];
          f = __builtin_amdgcn_mfma_f32_16x16x32_bf16(aq, bs_, f, 0, 0, 0);
        }
#pragma unroll
        for (int r = 0; r < 4; r++) f[r] *= eG_lds[mi * 16 + lg * 4 + r];
#pragma unroll
        for (int ks2 = 0; ks2 < 2; ks2++) {
          bf16x8 ap = *(bf16x8*)&P_lds[(mi * 16 + l15) * 72 + ks2 * 32 + lg * 8];
          f = __builtin_amdgcn_mfma_f32_16x16x32_bf16(ap, (ks2 == 0) ? av0 : av1, f, 0, 0, 0);
        }
        accout[mi] = f;
      }
      const float dcv = eG_lds[63];
#pragma unroll
      for (int ni2 = 0; ni2 < 8; ni2++) {
#pragma unroll
        for (int r = 0; r < 4; r++) streg[ni2][r] *= dcv;
        bf16x8 bk0 = *(bf16x8*)&kT_lds[(ni2 * 16 + l15) * 72 + lg * 8];
        bf16x8 bk1 = *(bf16x8*)&kT_lds[(ni2 * 16 + l15) * 72 + 32 + lg * 8];
        streg[ni2] = __builtin_amdgcn_mfma_f32_16x16x32_bf16(av0, bk0, streg[ni2], 0, 0, 0);
        streg[ni2] = __builtin_amdgcn_mfma_f32_16x16x32_bf16(av1, bk1, streg[ni2], 0, 0, 0);
      }
    }
    __syncthreads();

#pragma unroll
    for (int ni2 = 0; ni2 < 8; ni2++)
#pragma unroll
      for (int r = 0; r < 4; r++)
        St_lds[(w * 16 + lg * 4 + r) * 136 + ni2 * 16 + l15] = (bf16_t)streg[ni2][r];
#pragma unroll
    for (int mi = 0; mi < 4; mi++)
#pragma unroll
      for (int r = 0; r < 4; r++) {
        float v2 = accout[mi][r] * accout[mi][r];
        v2 += __shfl_xor(v2, 1);
        v2 += __shfl_xor(v2, 2);
        v2 += __shfl_xor(v2, 4);
        v2 += __shfl_xor(v2, 8);
        if (l15 == 0) rms_lds[(mi * 16 + lg * 4 + r) * 9 + w] = v2;
      }
    __syncthreads();
    if (tid < 64) {
      float tot = 0.f;
#pragma unroll
      for (int w2 = 0; w2 < 8; w2++) tot += rms_lds[tid * 9 + w2];
      rms_lds[tid * 9 + 8] = rsqrtf(tot * (1.f / 128.f) + 1e-6f);
    }
    __syncthreads();
    {
      const bf16_t* zrow = qkvz + (long)(b * 2048 + t0) * 8192 + 6144 + h * 128 + w * 16 + l15;
      bf16_t* arow = A2 + (long)(b * 2048 + t0) * 2048 + h * 128 + w * 16 + l15;
#pragma unroll
      for (int mi = 0; mi < 4; mi++)
#pragma unroll
        for (int r = 0; r < 4; r++) {
          const int tl = mi * 16 + lg * 4 + r;
          float z = (float)zrow[(long)tl * 8192];
          float gate = 1.f / (1.f + __expf(-z));
          arow[(long)tl * 2048] = (bf16_t)(accout[mi][r] * rms_lds[tl * 9 + 8] * nwl * gate);
        }
    }
  }
}

extern "C" void kernel_launch(void* const* d_in, const int* in_sizes, int n_in,
                              void* d_out, int out_size, void* d_ws, size_t ws_size,
                              hipStream_t stream) {
  const float* x      = (const float*)d_in[0];
  // d_in[1] = positions (unused)
  const float* W_qkvz = (const float*)d_in[2];
  const float* W_b    = (const float*)d_in[3];
  const float* W_a    = (const float*)d_in[4];
  const float* conv_w = (const float*)d_in[5];
  const float* norm_w = (const float*)d_in[6];
  const float* W_out  = (const float*)d_in[7];
  float* out = (float*)d_out;
  char* ws = (char*)d_ws;

  // Workspace layout identical to the passing round (244,580,352 bytes).
  bf16_t* qkvz  = (bf16_t*)(ws + 0);
  bf16_t* xb    = (bf16_t*)(ws + 134217728);
  bf16_t* qv    = (bf16_t*)(ws + 134217728);
  bf16_t* WqT   = (bf16_t*)(ws + 167772160);
  bf16_t* kv    = (bf16_t*)(ws + 167772160);
  bf16_t* vv    = (bf16_t*)(ws + 201326592);
  bf16_t* A2    = (bf16_t*)(ws + 201326592);
  bf16_t* WoT   = (bf16_t*)(ws + 234881024);
  float*  WbT   = (float*)(ws + 243269632);
  float*  WaT   = (float*)(ws + 243400704);
  float*  beta  = (float*)(ws + 243531776);
  float*  alpha = (float*)(ws + 244056064);

  if (ws_size < 244580352) return;

  k_cast_bf16<<<8192, 256, 0, stream>>>(x, xb);
  k_transpose_cast<<<dim3(8192 / 32, 2048 / 32), dim3(32, 8), 0, stream>>>(W_qkvz, WqT, 2048, 8192);
  k_transpose_cast<<<dim3(2048 / 32, 2048 / 32), dim3(32, 8), 0, stream>>>(W_out, WoT, 2048, 2048);
  k_transpose_f32<<<8, 256, 0, stream>>>(W_b, WbT, 2048, 16);
  k_transpose_f32<<<8, 256, 0, stream>>>(W_a, WaT, 2048, 16);
  k_beta_alpha<<<8192, 256, 0, stream>>>(x, WbT, WaT, beta, alpha);
  k_gemm_bt<bf16_t><<<dim3(64, 64), 256, 0, stream>>>(xb, WqT, qkvz, 8192, 8192, 2048);
  k_conv<<<8192, 256, 0, stream>>>(qkvz, conv_w, qv, kv, vv);
  k_tr_kv<<<2048, 256, 0, stream>>>(kv, vv, qkvz);
  k_scan_chunked<<<64, 512, 119040, stream>>>(qv, kv, qkvz, beta, alpha, norm_w, A2);
  k_gemm_bt<float><<<dim3(16, 64), 256, 0, stream>>>(A2, WoT, out, 8192, 2048, 2048);
  (void)in_sizes; (void)n_in; (void)out_size;
}

// Round 6
// 983.156 us; speedup vs baseline: 2.1835x; 1.1193x over previous
//
#include <hip/hip_runtime.h>
#include <hip/hip_bf16.h>

typedef __bf16 bf16_t;
typedef __attribute__((ext_vector_type(8))) __bf16 bf16x8;
typedef __attribute__((ext_vector_type(4))) float floatx4;

// Problem constants: B=4, T=2048, C=2048, H=16, D=128, QKV_DIM=6144, QKVZ=8192, BT=8192

__device__ __forceinline__ void gload16(const void* g, void* l) {
  __builtin_amdgcn_global_load_lds(
      (const __attribute__((address_space(1))) void*)g,
      (__attribute__((address_space(3))) void*)l, 16, 0, 0);
}

// ---------------- cast fp32 -> bf16 (vectorized) ----------------
__global__ __launch_bounds__(256) void k_cast_bf16(const float* __restrict__ in,
                                                   bf16_t* __restrict__ out) {
  long i = ((long)blockIdx.x * 256 + threadIdx.x) * 8;
  const float4 a = *(const float4*)(in + i);
  const float4 b = *(const float4*)(in + i + 4);
  bf16x8 o;
  o[0] = (bf16_t)a.x; o[1] = (bf16_t)a.y; o[2] = (bf16_t)a.z; o[3] = (bf16_t)a.w;
  o[4] = (bf16_t)b.x; o[5] = (bf16_t)b.y; o[6] = (bf16_t)b.z; o[7] = (bf16_t)b.w;
  *(bf16x8*)(out + i) = o;
}

// ---------------- transpose + cast fp32 -> bf16 ----------------
__global__ void k_transpose_cast(const float* __restrict__ in, bf16_t* __restrict__ out,
                                 int R, int Ccols) {
  __shared__ float tile[32][33];
  int c0 = blockIdx.x * 32, r0 = blockIdx.y * 32;
  for (int i = threadIdx.y; i < 32; i += 8)
    tile[i][threadIdx.x] = in[(long)(r0 + i) * Ccols + c0 + threadIdx.x];
  __syncthreads();
  for (int i = threadIdx.y; i < 32; i += 8)
    out[(long)(c0 + i) * R + r0 + threadIdx.x] = (bf16_t)tile[threadIdx.x][i];
}

// small fp32 transpose (for W_b / W_a: 2048x16 -> 16x2048)
__global__ void k_transpose_f32(const float* __restrict__ in, float* __restrict__ out,
                                int R, int Ccols) {
  int r = blockIdx.x * blockDim.x + threadIdx.x;
  if (r < R)
    for (int c = 0; c < Ccols; ++c) out[(long)c * R + r] = in[(long)r * Ccols + c];
}

// ---------------- beta/alpha: sigmoid(x @ W) ----------------
__global__ __launch_bounds__(256) void k_beta_alpha(const float* __restrict__ x,
                                                    const float* __restrict__ WbT,
                                                    const float* __restrict__ WaT,
                                                    float* __restrict__ beta,
                                                    float* __restrict__ alpha) {
  int row = blockIdx.x;  // b*T + t
  __shared__ float xs[2048];
  for (int i = threadIdx.x; i < 2048; i += 256) xs[i] = x[(long)row * 2048 + i];
  __syncthreads();
  int wave = threadIdx.x >> 6, lane = threadIdx.x & 63;
  for (int o = wave * 8; o < wave * 8 + 8; ++o) {
    const float* W = (o < 16) ? (WbT + (long)o * 2048) : (WaT + (long)(o - 16) * 2048);
    float s = 0.f;
    for (int k2 = lane; k2 < 2048; k2 += 64) s += xs[k2] * W[k2];
    for (int off = 32; off; off >>= 1) s += __shfl_down(s, off);
    if (lane == 0) {
      float sig = 1.f / (1.f + expf(-s));
      int b = row >> 11, t = row & 2047;
      int h = (o < 16) ? o : (o - 16);
      float* dst = (o < 16) ? beta : alpha;
      dst[((long)(b * 16 + h)) * 2048 + t] = sig;
    }
  }
}

// ---------------- bf16 MFMA GEMM: C = A @ Bt^T (m97 structure + XCD swizzle) -----------
// A: M x K row-major bf16 with row stride lda. Bt: N x K row-major bf16 (ldb=K).
// C: M x N row-major OUT_T. BM=BN=128, BK=32; 256 threads (4 waves 2x2), 4x4 frags/wave.
template <typename OUT_T>
__global__ __launch_bounds__(256) void k_gemm_bt(const bf16_t* __restrict__ A,
                                                 const bf16_t* __restrict__ Bt,
                                                 OUT_T* __restrict__ C, int M, int N, int K,
                                                 int lda) {
  constexpr int BK = 32;
  __shared__ alignas(16) bf16_t As[128 * BK];
  __shared__ alignas(16) bf16_t Bs[128 * BK];
  // XCD-aware bijective swizzle (grid size % 8 == 0): XCD k gets a contiguous work range.
  const int nwgx = gridDim.x;
  const int nwg = nwgx * gridDim.y;
  const int orig = blockIdx.y * nwgx + blockIdx.x;
  const int work = (orig & 7) * (nwg >> 3) + (orig >> 3);
  const int m0 = (work / nwgx) * 128, n0 = (work % nwgx) * 128;

  const int tid = threadIdx.x;
  const int wave = tid >> 6, lane = tid & 63;
  const int wr = wave >> 1, wc = wave & 1;
  const int lrow = lane & 15, lk = (lane >> 4) << 3;
  floatx4 acc[4][4] = {};

  const int srow0 = wave * 32 + (lane >> 2);
  const int scol = (lane & 3) * 8;
  const bf16_t* aptr = A + (long)(m0 + srow0) * lda + scol;
  const bf16_t* bptr = Bt + (long)(n0 + srow0) * K + scol;
  const long rstepA = 16 * (long)lda;
  const long rstepB = 16 * (long)K;
  bf16_t* as0 = &As[(wave * 32) * BK];
  bf16_t* as1 = &As[(wave * 32 + 16) * BK];
  bf16_t* bs0 = &Bs[(wave * 32) * BK];
  bf16_t* bs1 = &Bs[(wave * 32 + 16) * BK];

  for (int k0 = 0; k0 < K; k0 += BK) {
    __syncthreads();  // all waves done reading previous tile
    gload16(aptr + k0, as0);
    gload16(aptr + rstepA + k0, as1);
    gload16(bptr + k0, bs0);
    gload16(bptr + rstepB + k0, bs1);
    __syncthreads();  // vmcnt(0) drain before s_barrier -> data visible
    bf16x8 af[4], bfr[4];
#pragma unroll
    for (int i = 0; i < 4; i++) af[i] = *(const bf16x8*)&As[(wr * 64 + i * 16 + lrow) * BK + lk];
#pragma unroll
    for (int i = 0; i < 4; i++) bfr[i] = *(const bf16x8*)&Bs[(wc * 64 + i * 16 + lrow) * BK + lk];
#pragma unroll
    for (int mi = 0; mi < 4; mi++)
#pragma unroll
      for (int ni = 0; ni < 4; ni++)
        acc[mi][ni] = __builtin_amdgcn_mfma_f32_16x16x32_bf16(af[mi], bfr[ni], acc[mi][ni], 0, 0, 0);
  }
  const int crow_base = m0 + wr * 64 + (lane >> 4) * 4;
  const int ccol = n0 + wc * 64 + (lane & 15);
#pragma unroll
  for (int mi = 0; mi < 4; mi++)
#pragma unroll
    for (int ni = 0; ni < 4; ni++)
#pragma unroll
      for (int r = 0; r < 4; r++)
        C[(long)(crow_base + mi * 16 + r) * N + ccol + ni * 16] = (OUT_T)acc[mi][ni][r];
}

// ---------------- depthwise causal conv + SiLU + l2norm -> q,k,v (vectorized) ---------
__global__ __launch_bounds__(256) void k_conv(const bf16_t* __restrict__ qkvz,
                                              const float* __restrict__ conv_w,
                                              bf16_t* __restrict__ q, bf16_t* __restrict__ k,
                                              bf16_t* __restrict__ v) {
  int row = blockIdx.x;  // b*T + t
  int b = row >> 11, t = row & 2047;
  __shared__ float ys[6144];
  __shared__ float gsum[32][9];
  __shared__ float norms[32];
  const int c0 = threadIdx.x * 8;
  for (int c8 = c0; c8 < 6144; c8 += 2048) {
    bf16x8 xr[4];
#pragma unroll
    for (int w2 = 0; w2 < 4; ++w2) {
      int tt = t - 3 + w2;
      bf16x8 zr = {};
      xr[w2] = (tt >= 0) ? *(const bf16x8*)&qkvz[((long)(b * 2048 + tt)) * 8192 + c8] : zr;
    }
#pragma unroll
    for (int j = 0; j < 8; ++j) {
      float4 wv = *(const float4*)&conv_w[(c8 + j) * 4];
      float a = (float)xr[0][j] * wv.x + (float)xr[1][j] * wv.y +
                (float)xr[2][j] * wv.z + (float)xr[3][j] * wv.w;
      ys[c8 + j] = a / (1.f + __expf(-a));  // silu
    }
  }
  __syncthreads();
  {
    int g = threadIdx.x >> 3, j = threadIdx.x & 7;
    float s = 0.f;
#pragma unroll
    for (int e = 0; e < 16; ++e) {
      float yv = ys[g * 128 + j * 16 + e];
      s += yv * yv;
    }
    gsum[g][j] = s;
  }
  __syncthreads();
  if (threadIdx.x < 32) {
    float s = 0.f;
#pragma unroll
    for (int j = 0; j < 8; j++) s += gsum[threadIdx.x][j];
    norms[threadIdx.x] = 1.f / fmaxf(sqrtf(s), 1e-12f);
  }
  __syncthreads();
  for (int c8 = c0; c8 < 6144; c8 += 2048) {
    float scale;
    bf16_t* dst;
    if (c8 < 2048) {
      int h = c8 >> 7;
      scale = norms[h];
      dst = q + (((long)(b * 16 + h)) * 2048 + t) * 128 + (c8 & 127);
    } else if (c8 < 4096) {
      int h = (c8 - 2048) >> 7;
      scale = norms[16 + h];
      dst = k + (((long)(b * 16 + h)) * 2048 + t) * 128 + (c8 & 127);
    } else {
      scale = 1.f;
      int h = (c8 - 4096) >> 7;
      dst = v + (((long)(b * 16 + h)) * 2048 + t) * 128 + (c8 & 127);
    }
    bf16x8 o;
#pragma unroll
    for (int j = 0; j < 8; ++j) o[j] = (bf16_t)(ys[c8 + j] * scale);
    *(bf16x8*)dst = o;
  }
}

// ---------------- k,v natural -> kT,vT stripes inside dead qkvz region ----------------
// kT element (bh,dk,t) at qkvz elem (bh*128+dk)*8192 + 2048 + t
// vT element (bh,dv,t) at qkvz elem (bh*128+dv)*8192 + 4096 + t
__global__ __launch_bounds__(256) void k_tr_kv(const bf16_t* __restrict__ kv,
                                               const bf16_t* __restrict__ vv,
                                               bf16_t* __restrict__ qkvz) {
  __shared__ bf16_t t_lds[64 * 136];
  int bh = blockIdx.x >> 5, tc = blockIdx.x & 31;
  int t0 = tc * 64;
  int tid = threadIdx.x;
#pragma unroll
  for (int pass = 0; pass < 2; ++pass) {
    const bf16_t* src = (pass == 0 ? kv : vv) + (long)bh * 2048 * 128 + (long)t0 * 128;
    int r = tid >> 2, sc = (tid & 3) * 32;
    bf16x8 x0 = *(const bf16x8*)(src + (long)r * 128 + sc);
    bf16x8 x1 = *(const bf16x8*)(src + (long)r * 128 + sc + 8);
    bf16x8 x2 = *(const bf16x8*)(src + (long)r * 128 + sc + 16);
    bf16x8 x3 = *(const bf16x8*)(src + (long)r * 128 + sc + 24);
    __syncthreads();
    *(bf16x8*)&t_lds[r * 136 + sc] = x0;
    *(bf16x8*)&t_lds[r * 136 + sc + 8] = x1;
    *(bf16x8*)&t_lds[r * 136 + sc + 16] = x2;
    *(bf16x8*)&t_lds[r * 136 + sc + 24] = x3;
    __syncthreads();
    int d = tid >> 1, h2 = tid & 1;
    bf16_t* dst = qkvz + (long)(bh * 128 + d) * 8192 + (pass ? 4096 : 2048) + t0 + h2 * 32;
#pragma unroll
    for (int g = 0; g < 4; ++g) {
      bf16x8 o;
#pragma unroll
      for (int j = 0; j < 8; ++j) o[j] = t_lds[(h2 * 32 + g * 8 + j) * 136 + d];
      *(bf16x8*)(dst + g * 8) = o;
    }
  }
}

// ---------------- fused chunked gated-linear-attention scan (dv-split 4-way) ----------
// Grid (64 bh, 4 dvb), 512 threads = 8 waves. Wave w: g=w&1 (dv group of 16 rows within
// the block's 32-dv quarter), r=w>>1 (role: splits t-tiles mi and dk-tiles ni2).
// so output fp32: h<8 -> qkvz row stripe [0,4K) as fp32[1024]; h>=8 -> so_hi (vv) [1024]/row.
__global__ __launch_bounds__(512, 1) void k_scan_chunked(
    const bf16_t* __restrict__ qv, const bf16_t* __restrict__ kv,
    bf16_t* __restrict__ qkvz, float* __restrict__ so_hi,
    const float* __restrict__ beta, const float* __restrict__ alpha) {
  extern __shared__ char smem[];
  bf16_t* q_lds = (bf16_t*)smem;            // [64][136] = 17408 B
  bf16_t* kn_lds = q_lds + 8704;            // [64][136]
  bf16_t* kT_lds = kn_lds + 8704;           // [128][72] = 18432 B
  bf16_t* vT_lds = kT_lds + 9216;           // [32][72]  = 4608 B
  bf16_t* P_lds = vT_lds + 2304;            // [64][72]  = 9216 B
  bf16_t* St_lds = P_lds + 4608;            // [32][136] = 8704 B
  float* G_lds = (float*)(St_lds + 4352);   // [64]
  float* bet_lds = G_lds + 64;              // [64]
  float* w_lds = bet_lds + 64;              // [64] beta_s * exp(Gend - G_s)
  float* eG_lds = w_lds + 64;               // [64] exp(G_t)

  const int bh = blockIdx.x, dvb = blockIdx.y;
  const int b = bh >> 4, h = bh & 15;
  const int tid = threadIdx.x;
  const int w = tid >> 6, l = tid & 63;
  const int l15 = l & 15, lg = l >> 4;
  const int g = w & 1, r = w >> 1;

  const bf16_t* qb = qv + (long)bh * 2048 * 128;
  const bf16_t* kb = kv + (long)bh * 2048 * 128;
  const bf16_t* kTg = qkvz + (long)bh * 128 * 8192 + 2048;
  const bf16_t* vTg = qkvz + (long)(bh * 128 + dvb * 32) * 8192 + 4096;
  const float* bet = beta + (long)bh * 2048;
  const float* alp = alpha + (long)bh * 2048;

  floatx4 streg[2] = {};
  for (int i = tid; i < 2176; i += 512) ((float*)St_lds)[i] = 0.f;
  __syncthreads();

  const int sr = tid >> 3, ssc = (tid & 7) * 16;    // q/kn: 64 x 128
  const int sdk = tid >> 2, ssc2 = (tid & 3) * 16;  // kT: 128 x 64

  for (int c = 0; c < 32; ++c) {
    const int t0 = c * 64;
    // ---- phase A: stage tiles + (wave0) decay math ----
    {
      const bf16_t* qs = qb + (long)(t0 + sr) * 128 + ssc;
      const bf16_t* ks = kb + (long)(t0 + sr) * 128 + ssc;
      const bf16_t* kts = kTg + (long)sdk * 8192 + t0 + ssc2;
      bf16x8 a0 = *(const bf16x8*)qs, a1 = *(const bf16x8*)(qs + 8);
      bf16x8 b0 = *(const bf16x8*)ks, b1 = *(const bf16x8*)(ks + 8);
      bf16x8 c0 = *(const bf16x8*)kts, c1 = *(const bf16x8*)(kts + 8);
      *(bf16x8*)&q_lds[sr * 136 + ssc] = a0;
      *(bf16x8*)&q_lds[sr * 136 + ssc + 8] = a1;
      *(bf16x8*)&kn_lds[sr * 136 + ssc] = b0;
      *(bf16x8*)&kn_lds[sr * 136 + ssc + 8] = b1;
      *(bf16x8*)&kT_lds[sdk * 72 + ssc2] = c0;
      *(bf16x8*)&kT_lds[sdk * 72 + ssc2 + 8] = c1;
      if (tid < 256) {
        int svr = tid >> 3, svc = (tid & 7) * 8;
        bf16x8 d0 = *(const bf16x8*)(vTg + (long)svr * 8192 + t0 + svc);
        *(bf16x8*)&vT_lds[svr * 72 + svc] = d0;
      }
      if (w == 0) {
        float bsv = bet[t0 + l];
        float la = __logf(alp[t0 + l]);
#pragma unroll
        for (int off = 1; off < 64; off <<= 1) {
          float xup = __shfl_up(la, off);
          if (l >= off) la += xup;
        }
        float ge = __shfl(la, 63);
        G_lds[l] = la;
        bet_lds[l] = bsv;
        w_lds[l] = bsv * __expf(ge - la);
        eG_lds[l] = __expf(la);
      }
    }
    __syncthreads();  // b1

    // ---- phase B: scale kT in place (each thread scales what it staged) ----
    {
      bf16_t* p = &kT_lds[sdk * 72 + ssc2];
      bf16x8 x0 = *(bf16x8*)p, x1 = *(bf16x8*)(p + 8);
#pragma unroll
      for (int j = 0; j < 8; j++) {
        x0[j] = (bf16_t)((float)x0[j] * w_lds[ssc2 + j]);
        x1[j] = (bf16_t)((float)x1[j] * w_lds[ssc2 + 8 + j]);
      }
      *(bf16x8*)p = x0;
      *(bf16x8*)(p + 8) = x1;
    }

    // ---- phase CD: score = q K^T (2 tiles/wave), build P ----
    {
      const int mi = w >> 1;
      bf16x8 aq[4];
#pragma unroll
      for (int ks = 0; ks < 4; ks++)
        aq[ks] = *(bf16x8*)&q_lds[(mi * 16 + l15) * 136 + ks * 32 + lg * 8];
#pragma unroll
      for (int sn2 = 0; sn2 < 2; sn2++) {
        const int sn = (w & 1) * 2 + sn2;
        floatx4 sc_ = {0.f, 0.f, 0.f, 0.f};
#pragma unroll
        for (int ks = 0; ks < 4; ks++) {
          bf16x8 bk = *(bf16x8*)&kn_lds[(sn * 16 + l15) * 136 + ks * 32 + lg * 8];
          sc_ = __builtin_amdgcn_mfma_f32_16x16x32_bf16(aq[ks], bk, sc_, 0, 0, 0);
        }
        const int sl = sn * 16 + l15;
        const float gs = G_lds[sl], bs = bet_lds[sl];
#pragma unroll
        for (int rr = 0; rr < 4; rr++) {
          const int tl = mi * 16 + lg * 4 + rr;
          float val = (sl <= tl) ? sc_[rr] * __expf(G_lds[tl] - gs) * bs : 0.f;
          P_lds[tl * 72 + sl] = (bf16_t)val;
        }
      }
    }
    __syncthreads();  // b3

    // ---- phase E: out(mi=r) = exp(Gt)*(q@S_in) + P@V ; state update (ni2 = 2r,2r+1) ----
    floatx4 acco = {0.f, 0.f, 0.f, 0.f};
    {
      const int rloc = g * 16 + l15;  // local dv row (block quarter)
      bf16x8 av0 = *(bf16x8*)&vT_lds[rloc * 72 + lg * 8];
      bf16x8 av1 = *(bf16x8*)&vT_lds[rloc * 72 + 32 + lg * 8];
      floatx4 f = {0.f, 0.f, 0.f, 0.f};
#pragma unroll
      for (int ks = 0; ks < 4; ks++) {
        bf16x8 aq = *(bf16x8*)&q_lds[(r * 16 + l15) * 136 + ks * 32 + lg * 8];
        bf16x8 bs_ = *(bf16x8*)&St_lds[rloc * 136 + ks * 32 + lg * 8];
        f = __builtin_amdgcn_mfma_f32_16x16x32_bf16(aq, bs_, f, 0, 0, 0);
      }
#pragma unroll
      for (int rr = 0; rr < 4; rr++) f[rr] *= eG_lds[r * 16 + lg * 4 + rr];
#pragma unroll
      for (int ks2 = 0; ks2 < 2; ks2++) {
        bf16x8 ap = *(bf16x8*)&P_lds[(r * 16 + l15) * 72 + ks2 * 32 + lg * 8];
        f = __builtin_amdgcn_mfma_f32_16x16x32_bf16(ap, (ks2 == 0) ? av0 : av1, f, 0, 0, 0);
      }
      acco = f;
      const float dcv = eG_lds[63];
#pragma unroll
      for (int ni = 0; ni < 2; ni++) {
        const int ni2 = r * 2 + ni;
#pragma unroll
        for (int rr = 0; rr < 4; rr++) streg[ni][rr] *= dcv;
        bf16x8 bk0 = *(bf16x8*)&kT_lds[(ni2 * 16 + l15) * 72 + lg * 8];
        bf16x8 bk1 = *(bf16x8*)&kT_lds[(ni2 * 16 + l15) * 72 + 32 + lg * 8];
        streg[ni] = __builtin_amdgcn_mfma_f32_16x16x32_bf16(av0, bk0, streg[ni], 0, 0, 0);
        streg[ni] = __builtin_amdgcn_mfma_f32_16x16x32_bf16(av1, bk1, streg[ni], 0, 0, 0);
      }
    }
    __syncthreads();  // b4

    // ---- phase F: publish new state + so write ----
#pragma unroll
    for (int ni = 0; ni < 2; ni++) {
      const int ni2 = r * 2 + ni;
#pragma unroll
      for (int rr = 0; rr < 4; rr++)
        St_lds[(g * 16 + lg * 4 + rr) * 136 + ni2 * 16 + l15] = (bf16_t)streg[ni][rr];
    }
    {
      const int dvg = dvb * 32 + g * 16 + l15;
      const int hcol = h * 128 + dvg;  // 0..2047
#pragma unroll
      for (int rr = 0; rr < 4; rr++) {
        const int t = t0 + r * 16 + lg * 4 + rr;
        const long row = (long)b * 2048 + t;
        if (hcol < 1024)
          ((float*)qkvz)[row * 4096 + hcol] = acco[rr];
        else
          so_hi[row * 1024 + hcol - 1024] = acco[rr];
      }
    }
    // next phase A writes q/kn/kT/vT (not read after b4); St reads separated by b1+b3.
  }
}

// ---------------- RMS norm + gate(z) -> A2 (qkvz stripe [4K,8K)) ----------------
__global__ __launch_bounds__(256) void k_rmsgate(const float* __restrict__ so_hi,
                                                 bf16_t* __restrict__ qkvz,
                                                 const float* __restrict__ norm_w) {
  long row = blockIdx.x;  // b*T + t
  int tid = threadIdx.x;
  int h = tid >> 4, j = tid & 15;
  const float* srow = (h < 8) ? (const float*)qkvz + row * 4096 + h * 128 + j * 8
                              : so_hi + row * 1024 + (h - 8) * 128 + j * 8;
  float xv[8];
  *(float4*)&xv[0] = *(const float4*)srow;
  *(float4*)&xv[4] = *(const float4*)(srow + 4);
  float ss = 0.f;
#pragma unroll
  for (int e = 0; e < 8; e++) ss += xv[e] * xv[e];
  ss += __shfl_xor(ss, 1); ss += __shfl_xor(ss, 2);
  ss += __shfl_xor(ss, 4); ss += __shfl_xor(ss, 8);
  float rinv = rsqrtf(ss * (1.0f / 128.0f) + 1e-6f);
  const bf16_t* zrow = qkvz + row * 8192 + 6144 + h * 128 + j * 8;
  bf16x8 zv = *(const bf16x8*)zrow;
  bf16x8 o;
#pragma unroll
  for (int e = 0; e < 8; e++) {
    float z = (float)zv[e];
    float gate = 1.f / (1.f + __expf(-z));
    o[e] = (bf16_t)(xv[e] * rinv * norm_w[j * 8 + e] * gate);
  }
  *(bf16x8*)(qkvz + row * 8192 + 2048 + h * 128 + j * 8) = o;
}

extern "C" void kernel_launch(void* const* d_in, const int* in_sizes, int n_in,
                              void* d_out, int out_size, void* d_ws, size_t ws_size,
                              hipStream_t stream) {
  const float* x      = (const float*)d_in[0];
  // d_in[1] = positions (unused)
  const float* W_qkvz = (const float*)d_in[2];
  const float* W_b    = (const float*)d_in[3];
  const float* W_a    = (const float*)d_in[4];
  const float* conv_w = (const float*)d_in[5];
  const float* norm_w = (const float*)d_in[6];
  const float* W_out  = (const float*)d_in[7];
  float* out = (float*)d_out;
  char* ws = (char*)d_ws;

  // Workspace layout (244,580,352 bytes). qkvz row (16 KB) lifecycle:
  //  [0,4K): qkv cols (dead post-conv) -> so_lo fp32[1024] (scan -> rmsgate)
  //  [4K,8K): kT stripe (tr_kv -> scan) -> A2 bf16[2048] (rmsgate -> gemm2, lda=8192)
  //  [8K,12K): vT stripe (tr_kv -> scan)
  //  [12K,16K): z (gemm1 -> rmsgate)
  // vv: v natural (conv -> tr_kv) -> so_hi fp32 (scan -> rmsgate), 32 MB of its 33.5 MB.
  bf16_t* qkvz  = (bf16_t*)(ws + 0);
  bf16_t* xb    = (bf16_t*)(ws + 134217728);
  bf16_t* qv    = (bf16_t*)(ws + 134217728);   // aliases xb
  bf16_t* WqT   = (bf16_t*)(ws + 167772160);
  bf16_t* kv    = (bf16_t*)(ws + 167772160);   // aliases WqT
  bf16_t* vv    = (bf16_t*)(ws + 201326592);
  float*  so_hi = (float*)(ws + 201326592);    // aliases vv
  bf16_t* WoT   = (bf16_t*)(ws + 234881024);
  float*  WbT   = (float*)(ws + 243269632);
  float*  WaT   = (float*)(ws + 243400704);
  float*  beta  = (float*)(ws + 243531776);
  float*  alpha = (float*)(ws + 244056064);

  if (ws_size < 244580352) return;

  k_cast_bf16<<<8192, 256, 0, stream>>>(x, xb);
  k_transpose_cast<<<dim3(8192 / 32, 2048 / 32), dim3(32, 8), 0, stream>>>(W_qkvz, WqT, 2048, 8192);
  k_transpose_cast<<<dim3(2048 / 32, 2048 / 32), dim3(32, 8), 0, stream>>>(W_out, WoT, 2048, 2048);
  k_transpose_f32<<<8, 256, 0, stream>>>(W_b, WbT, 2048, 16);
  k_transpose_f32<<<8, 256, 0, stream>>>(W_a, WaT, 2048, 16);
  k_beta_alpha<<<8192, 256, 0, stream>>>(x, WbT, WaT, beta, alpha);
  k_gemm_bt<bf16_t><<<dim3(64, 64), 256, 0, stream>>>(xb, WqT, qkvz, 8192, 8192, 2048, 2048);
  k_conv<<<8192, 256, 0, stream>>>(qkvz, conv_w, qv, kv, vv);
  k_tr_kv<<<2048, 256, 0, stream>>>(kv, vv, qkvz);
  k_scan_chunked<<<dim3(64, 4), 512, 76800, stream>>>(qv, kv, qkvz, so_hi, beta, alpha);
  k_rmsgate<<<8192, 256, 0, stream>>>(so_hi, qkvz, norm_w);
  k_gemm_bt<float><<<dim3(16, 64), 256, 0, stream>>>(qkvz + 2048, WoT, out, 8192, 2048, 2048, 8192);
  (void)in_sizes; (void)n_in; (void)out_size;
}

// Round 7
// 914.900 us; speedup vs baseline: 2.3464x; 1.0746x over previous
//
#include <hip/hip_runtime.h>
#include <hip/hip_bf16.h>

typedef __bf16 bf16_t;
typedef __attribute__((ext_vector_type(8))) __bf16 bf16x8;
typedef __attribute__((ext_vector_type(4))) float floatx4;

// Problem constants: B=4, T=2048, C=2048, H=16, D=128, QKV_DIM=6144, QKVZ=8192, BT=8192

__device__ __forceinline__ void gload16(const void* g, void* l) {
  __builtin_amdgcn_global_load_lds(
      (const __attribute__((address_space(1))) void*)g,
      (__attribute__((address_space(3))) void*)l, 16, 0, 0);
}

// ---------------- cast fp32 -> bf16 (vectorized) ----------------
__global__ __launch_bounds__(256) void k_cast_bf16(const float* __restrict__ in,
                                                   bf16_t* __restrict__ out) {
  long i = ((long)blockIdx.x * 256 + threadIdx.x) * 8;
  const float4 a = *(const float4*)(in + i);
  const float4 b = *(const float4*)(in + i + 4);
  bf16x8 o;
  o[0] = (bf16_t)a.x; o[1] = (bf16_t)a.y; o[2] = (bf16_t)a.z; o[3] = (bf16_t)a.w;
  o[4] = (bf16_t)b.x; o[5] = (bf16_t)b.y; o[6] = (bf16_t)b.z; o[7] = (bf16_t)b.w;
  *(bf16x8*)(out + i) = o;
}

// ---------------- transpose + cast fp32 -> bf16 ----------------
__global__ void k_transpose_cast(const float* __restrict__ in, bf16_t* __restrict__ out,
                                 int R, int Ccols) {
  __shared__ float tile[32][33];
  int c0 = blockIdx.x * 32, r0 = blockIdx.y * 32;
  for (int i = threadIdx.y; i < 32; i += 8)
    tile[i][threadIdx.x] = in[(long)(r0 + i) * Ccols + c0 + threadIdx.x];
  __syncthreads();
  for (int i = threadIdx.y; i < 32; i += 8)
    out[(long)(c0 + i) * R + r0 + threadIdx.x] = (bf16_t)tile[threadIdx.x][i];
}

// small fp32 transpose (for W_b / W_a: 2048x16 -> 16x2048)
__global__ void k_transpose_f32(const float* __restrict__ in, float* __restrict__ out,
                                int R, int Ccols) {
  int r = blockIdx.x * blockDim.x + threadIdx.x;
  if (r < R)
    for (int c = 0; c < Ccols; ++c) out[(long)c * R + r] = in[(long)r * Ccols + c];
}

// ---------------- beta/alpha: sigmoid(x @ W) ----------------
__global__ __launch_bounds__(256) void k_beta_alpha(const float* __restrict__ x,
                                                    const float* __restrict__ WbT,
                                                    const float* __restrict__ WaT,
                                                    float* __restrict__ beta,
                                                    float* __restrict__ alpha) {
  int row = blockIdx.x;  // b*T + t
  __shared__ float xs[2048];
  for (int i = threadIdx.x; i < 2048; i += 256) xs[i] = x[(long)row * 2048 + i];
  __syncthreads();
  int wave = threadIdx.x >> 6, lane = threadIdx.x & 63;
  for (int o = wave * 8; o < wave * 8 + 8; ++o) {
    const float* W = (o < 16) ? (WbT + (long)o * 2048) : (WaT + (long)(o - 16) * 2048);
    float s = 0.f;
    for (int k2 = lane; k2 < 2048; k2 += 64) s += xs[k2] * W[k2];
    for (int off = 32; off; off >>= 1) s += __shfl_down(s, off);
    if (lane == 0) {
      float sig = 1.f / (1.f + expf(-s));
      int b = row >> 11, t = row & 2047;
      int h = (o < 16) ? o : (o - 16);
      float* dst = (o < 16) ? beta : alpha;
      dst[((long)(b * 16 + h)) * 2048 + t] = sig;
    }
  }
}

// ---------------- bf16 MFMA GEMM 256x256: C = A @ Bt^T ----------------
// A: M x K row-major bf16 (row stride lda). Bt: N x K row-major bf16 (ldb = K).
// C: M x N row-major OUT_T. BM=BN=256, BK=64, 512 threads = 8 waves (2M x 4N),
// per-wave 128x64 output = acc[8][4] 16x16 frags. LDS: double-buffered A/B tiles
// [256 rows][64 cols] bf16 (128 B/row), 128 KiB total, 1 block/CU.
// T2 swizzle: logical 16B chunk (row, c) lives at LDS chunk (row, c ^ (row&7));
// global_load_lds dest is LINEAR (c*16 per thread), the inverse permutation is
// applied to the per-lane GLOBAL source column (rule 21), reads use the XOR.
// Pipeline: single __syncthreads per K-step; STAGE(kt+2) issued after the barrier,
// drained by the NEXT iteration's barrier => every drain is covered by a full
// 64-MFMA compute phase (never drains just-issued loads).
template <typename OUT_T>
__global__ __launch_bounds__(512, 2) void k_gemm256(const bf16_t* __restrict__ A,
                                                    const bf16_t* __restrict__ Bt,
                                                    OUT_T* __restrict__ C,
                                                    int N, int K, int lda) {
  extern __shared__ char gsm[];  // [buf0: A 32K | B 32K][buf1: A 32K | B 32K]
  const int m0 = blockIdx.y * 256, n0 = blockIdx.x * 256;
  const int tid = threadIdx.x;
  const int w = tid >> 6, l = tid & 63;
  const int wm = w >> 2, wn = w & 3;
  const int l15 = l & 15, lg = l >> 4;

  // staging: 4 chunks per matrix per thread; chunk id c = t*512+tid; dest byte c*16
  const bf16_t* asrc[4];
  const bf16_t* bsrc[4];
  int dofs[4];
#pragma unroll
  for (int t = 0; t < 4; ++t) {
    int c = t * 512 + tid;
    int row = c >> 3, cs = (c & 7) ^ (row & 7);  // pre-swizzled source chunk
    asrc[t] = A + (long)(m0 + row) * lda + cs * 8;
    bsrc[t] = Bt + (long)(n0 + row) * K + cs * 8;
    dofs[t] = c * 16;
  }

  auto STAGE = [&](int buf, int k0) {
    char* ab = gsm + buf * 65536;
    char* bb = ab + 32768;
#pragma unroll
    for (int t = 0; t < 4; ++t) {
      gload16(asrc[t] + k0, ab + dofs[t]);
      gload16(bsrc[t] + k0, bb + dofs[t]);
    }
  };

  floatx4 acc[8][4] = {};
  STAGE(0, 0);
  STAGE(1, 64);
  const int NK = K >> 6;
  for (int kt = 0; kt < NK; ++kt) {
    __syncthreads();  // drain own vmem (covered by prev compute) + rendezvous
    const char* As_ = gsm + (kt & 1) * 65536;
    const char* Bs_ = As_ + 32768;
#pragma unroll
    for (int ks = 0; ks < 2; ++ks) {
      bf16x8 af[8], bfr[4];
#pragma unroll
      for (int mi = 0; mi < 8; ++mi) {
        const int r = wm * 128 + mi * 16 + l15;
        af[mi] = *(const bf16x8*)(As_ + r * 128 + ((((ks << 2) + lg) ^ (r & 7)) << 4));
      }
#pragma unroll
      for (int ni = 0; ni < 4; ++ni) {
        const int r = wn * 64 + ni * 16 + l15;
        bfr[ni] = *(const bf16x8*)(Bs_ + r * 128 + ((((ks << 2) + lg) ^ (r & 7)) << 4));
      }
      __builtin_amdgcn_s_setprio(1);
#pragma unroll
      for (int mi = 0; mi < 8; ++mi)
#pragma unroll
        for (int ni = 0; ni < 4; ++ni)
          acc[mi][ni] = __builtin_amdgcn_mfma_f32_16x16x32_bf16(af[mi], bfr[ni], acc[mi][ni], 0, 0, 0);
      __builtin_amdgcn_s_setprio(0);
    }
    __syncthreads();  // all waves done reading buf[kt&1]
    if (kt + 2 < NK) STAGE(kt & 1, (kt + 2) << 6);  // refill freed buffer; drains next iter
  }
  // Epilogue: C/D layout row=(l>>4)*4+r, col=l&15 [m89-verified]
  const int crow0 = m0 + wm * 128 + lg * 4;
  const int ccol = n0 + wn * 64 + l15;
#pragma unroll
  for (int mi = 0; mi < 8; ++mi)
#pragma unroll
    for (int ni = 0; ni < 4; ++ni)
#pragma unroll
      for (int r = 0; r < 4; ++r)
        C[(long)(crow0 + mi * 16 + r) * N + ccol + ni * 16] = (OUT_T)acc[mi][ni][r];
}

// ---------------- depthwise causal conv + SiLU + l2norm -> q,k,v (vectorized) ---------
__global__ __launch_bounds__(256) void k_conv(const bf16_t* __restrict__ qkvz,
                                              const float* __restrict__ conv_w,
                                              bf16_t* __restrict__ q, bf16_t* __restrict__ k,
                                              bf16_t* __restrict__ v) {
  int row = blockIdx.x;  // b*T + t
  int b = row >> 11, t = row & 2047;
  __shared__ float ys[6144];
  __shared__ float gsum[32][9];
  __shared__ float norms[32];
  const int c0 = threadIdx.x * 8;
  for (int c8 = c0; c8 < 6144; c8 += 2048) {
    bf16x8 xr[4];
#pragma unroll
    for (int w2 = 0; w2 < 4; ++w2) {
      int tt = t - 3 + w2;
      bf16x8 zr = {};
      xr[w2] = (tt >= 0) ? *(const bf16x8*)&qkvz[((long)(b * 2048 + tt)) * 8192 + c8] : zr;
    }
#pragma unroll
    for (int j = 0; j < 8; ++j) {
      float4 wv = *(const float4*)&conv_w[(c8 + j) * 4];
      float a = (float)xr[0][j] * wv.x + (float)xr[1][j] * wv.y +
                (float)xr[2][j] * wv.z + (float)xr[3][j] * wv.w;
      ys[c8 + j] = a / (1.f + __expf(-a));  // silu
    }
  }
  __syncthreads();
  {
    int g = threadIdx.x >> 3, j = threadIdx.x & 7;
    float s = 0.f;
#pragma unroll
    for (int e = 0; e < 16; ++e) {
      float yv = ys[g * 128 + j * 16 + e];
      s += yv * yv;
    }
    gsum[g][j] = s;
  }
  __syncthreads();
  if (threadIdx.x < 32) {
    float s = 0.f;
#pragma unroll
    for (int j = 0; j < 8; j++) s += gsum[threadIdx.x][j];
    norms[threadIdx.x] = 1.f / fmaxf(sqrtf(s), 1e-12f);
  }
  __syncthreads();
  for (int c8 = c0; c8 < 6144; c8 += 2048) {
    float scale;
    bf16_t* dst;
    if (c8 < 2048) {
      int h = c8 >> 7;
      scale = norms[h];
      dst = q + (((long)(b * 16 + h)) * 2048 + t) * 128 + (c8 & 127);
    } else if (c8 < 4096) {
      int h = (c8 - 2048) >> 7;
      scale = norms[16 + h];
      dst = k + (((long)(b * 16 + h)) * 2048 + t) * 128 + (c8 & 127);
    } else {
      scale = 1.f;
      int h = (c8 - 4096) >> 7;
      dst = v + (((long)(b * 16 + h)) * 2048 + t) * 128 + (c8 & 127);
    }
    bf16x8 o;
#pragma unroll
    for (int j = 0; j < 8; ++j) o[j] = (bf16_t)(ys[c8 + j] * scale);
    *(bf16x8*)dst = o;
  }
}

// ---------------- k,v natural -> kT,vT stripes inside dead qkvz region ----------------
// kT element (bh,dk,t) at qkvz elem (bh*128+dk)*8192 + 2048 + t
// vT element (bh,dv,t) at qkvz elem (bh*128+dv)*8192 + 4096 + t
__global__ __launch_bounds__(256) void k_tr_kv(const bf16_t* __restrict__ kv,
                                               const bf16_t* __restrict__ vv,
                                               bf16_t* __restrict__ qkvz) {
  __shared__ bf16_t t_lds[64 * 136];
  int bh = blockIdx.x >> 5, tc = blockIdx.x & 31;
  int t0 = tc * 64;
  int tid = threadIdx.x;
#pragma unroll
  for (int pass = 0; pass < 2; ++pass) {
    const bf16_t* src = (pass == 0 ? kv : vv) + (long)bh * 2048 * 128 + (long)t0 * 128;
    int r = tid >> 2, sc = (tid & 3) * 32;
    bf16x8 x0 = *(const bf16x8*)(src + (long)r * 128 + sc);
    bf16x8 x1 = *(const bf16x8*)(src + (long)r * 128 + sc + 8);
    bf16x8 x2 = *(const bf16x8*)(src + (long)r * 128 + sc + 16);
    bf16x8 x3 = *(const bf16x8*)(src + (long)r * 128 + sc + 24);
    __syncthreads();
    *(bf16x8*)&t_lds[r * 136 + sc] = x0;
    *(bf16x8*)&t_lds[r * 136 + sc + 8] = x1;
    *(bf16x8*)&t_lds[r * 136 + sc + 16] = x2;
    *(bf16x8*)&t_lds[r * 136 + sc + 24] = x3;
    __syncthreads();
    int d = tid >> 1, h2 = tid & 1;
    bf16_t* dst = qkvz + (long)(bh * 128 + d) * 8192 + (pass ? 4096 : 2048) + t0 + h2 * 32;
#pragma unroll
    for (int g = 0; g < 4; ++g) {
      bf16x8 o;
#pragma unroll
      for (int j = 0; j < 8; ++j) o[j] = t_lds[(h2 * 32 + g * 8 + j) * 136 + d];
      *(bf16x8*)(dst + g * 8) = o;
    }
  }
}

// ---------------- fused chunked gated-linear-attention scan (dv-split 4-way) ----------
// Grid (64 bh, 4 dvb), 512 threads = 8 waves. Wave w: g=w&1 (dv group of 16 rows within
// the block's 32-dv quarter), r=w>>1 (role: splits t-tiles mi and dk-tiles ni2).
// so output fp32: h<8 -> qkvz row stripe [0,4K) as fp32[1024]; h>=8 -> so_hi (vv) [1024]/row.
__global__ __launch_bounds__(512, 1) void k_scan_chunked(
    const bf16_t* __restrict__ qv, const bf16_t* __restrict__ kv,
    bf16_t* __restrict__ qkvz, float* __restrict__ so_hi,
    const float* __restrict__ beta, const float* __restrict__ alpha) {
  extern __shared__ char smem[];
  bf16_t* q_lds = (bf16_t*)smem;            // [64][136] = 17408 B
  bf16_t* kn_lds = q_lds + 8704;            // [64][136]
  bf16_t* kT_lds = kn_lds + 8704;           // [128][72] = 18432 B
  bf16_t* vT_lds = kT_lds + 9216;           // [32][72]  = 4608 B
  bf16_t* P_lds = vT_lds + 2304;            // [64][72]  = 9216 B
  bf16_t* St_lds = P_lds + 4608;            // [32][136] = 8704 B
  float* G_lds = (float*)(St_lds + 4352);   // [64]
  float* bet_lds = G_lds + 64;              // [64]
  float* w_lds = bet_lds + 64;              // [64] beta_s * exp(Gend - G_s)
  float* eG_lds = w_lds + 64;               // [64] exp(G_t)

  const int bh = blockIdx.x, dvb = blockIdx.y;
  const int b = bh >> 4, h = bh & 15;
  const int tid = threadIdx.x;
  const int w = tid >> 6, l = tid & 63;
  const int l15 = l & 15, lg = l >> 4;
  const int g = w & 1, r = w >> 1;

  const bf16_t* qb = qv + (long)bh * 2048 * 128;
  const bf16_t* kb = kv + (long)bh * 2048 * 128;
  const bf16_t* kTg = qkvz + (long)bh * 128 * 8192 + 2048;
  const bf16_t* vTg = qkvz + (long)(bh * 128 + dvb * 32) * 8192 + 4096;
  const float* bet = beta + (long)bh * 2048;
  const float* alp = alpha + (long)bh * 2048;

  floatx4 streg[2] = {};
  for (int i = tid; i < 2176; i += 512) ((float*)St_lds)[i] = 0.f;
  __syncthreads();

  const int sr = tid >> 3, ssc = (tid & 7) * 16;    // q/kn: 64 x 128
  const int sdk = tid >> 2, ssc2 = (tid & 3) * 16;  // kT: 128 x 64

  for (int c = 0; c < 32; ++c) {
    const int t0 = c * 64;
    // ---- phase A: stage tiles + (wave0) decay math ----
    {
      const bf16_t* qs = qb + (long)(t0 + sr) * 128 + ssc;
      const bf16_t* ks = kb + (long)(t0 + sr) * 128 + ssc;
      const bf16_t* kts = kTg + (long)sdk * 8192 + t0 + ssc2;
      bf16x8 a0 = *(const bf16x8*)qs, a1 = *(const bf16x8*)(qs + 8);
      bf16x8 b0 = *(const bf16x8*)ks, b1 = *(const bf16x8*)(ks + 8);
      bf16x8 c0 = *(const bf16x8*)kts, c1 = *(const bf16x8*)(kts + 8);
      *(bf16x8*)&q_lds[sr * 136 + ssc] = a0;
      *(bf16x8*)&q_lds[sr * 136 + ssc + 8] = a1;
      *(bf16x8*)&kn_lds[sr * 136 + ssc] = b0;
      *(bf16x8*)&kn_lds[sr * 136 + ssc + 8] = b1;
      *(bf16x8*)&kT_lds[sdk * 72 + ssc2] = c0;
      *(bf16x8*)&kT_lds[sdk * 72 + ssc2 + 8] = c1;
      if (tid < 256) {
        int svr = tid >> 3, svc = (tid & 7) * 8;
        bf16x8 d0 = *(const bf16x8*)(vTg + (long)svr * 8192 + t0 + svc);
        *(bf16x8*)&vT_lds[svr * 72 + svc] = d0;
      }
      if (w == 0) {
        float bsv = bet[t0 + l];
        float la = __logf(alp[t0 + l]);
#pragma unroll
        for (int off = 1; off < 64; off <<= 1) {
          float xup = __shfl_up(la, off);
          if (l >= off) la += xup;
        }
        float ge = __shfl(la, 63);
        G_lds[l] = la;
        bet_lds[l] = bsv;
        w_lds[l] = bsv * __expf(ge - la);
        eG_lds[l] = __expf(la);
      }
    }
    __syncthreads();  // b1

    // ---- phase B: scale kT in place (each thread scales what it staged) ----
    {
      bf16_t* p = &kT_lds[sdk * 72 + ssc2];
      bf16x8 x0 = *(bf16x8*)p, x1 = *(bf16x8*)(p + 8);
#pragma unroll
      for (int j = 0; j < 8; j++) {
        x0[j] = (bf16_t)((float)x0[j] * w_lds[ssc2 + j]);
        x1[j] = (bf16_t)((float)x1[j] * w_lds[ssc2 + 8 + j]);
      }
      *(bf16x8*)p = x0;
      *(bf16x8*)(p + 8) = x1;
    }

    // ---- phase CD: score = q K^T (2 tiles/wave), build P ----
    {
      const int mi = w >> 1;
      bf16x8 aq[4];
#pragma unroll
      for (int ks = 0; ks < 4; ks++)
        aq[ks] = *(bf16x8*)&q_lds[(mi * 16 + l15) * 136 + ks * 32 + lg * 8];
#pragma unroll
      for (int sn2 = 0; sn2 < 2; sn2++) {
        const int sn = (w & 1) * 2 + sn2;
        floatx4 sc_ = {0.f, 0.f, 0.f, 0.f};
#pragma unroll
        for (int ks = 0; ks < 4; ks++) {
          bf16x8 bk = *(bf16x8*)&kn_lds[(sn * 16 + l15) * 136 + ks * 32 + lg * 8];
          sc_ = __builtin_amdgcn_mfma_f32_16x16x32_bf16(aq[ks], bk, sc_, 0, 0, 0);
        }
        const int sl = sn * 16 + l15;
        const float gs = G_lds[sl], bs = bet_lds[sl];
#pragma unroll
        for (int rr = 0; rr < 4; rr++) {
          const int tl = mi * 16 + lg * 4 + rr;
          float val = (sl <= tl) ? sc_[rr] * __expf(G_lds[tl] - gs) * bs : 0.f;
          P_lds[tl * 72 + sl] = (bf16_t)val;
        }
      }
    }
    __syncthreads();  // b3

    // ---- phase E: out(mi=r) = exp(Gt)*(q@S_in) + P@V ; state update (ni2 = 2r,2r+1) ----
    floatx4 acco = {0.f, 0.f, 0.f, 0.f};
    {
      const int rloc = g * 16 + l15;  // local dv row (block quarter)
      bf16x8 av0 = *(bf16x8*)&vT_lds[rloc * 72 + lg * 8];
      bf16x8 av1 = *(bf16x8*)&vT_lds[rloc * 72 + 32 + lg * 8];
      floatx4 f = {0.f, 0.f, 0.f, 0.f};
#pragma unroll
      for (int ks = 0; ks < 4; ks++) {
        bf16x8 aq = *(bf16x8*)&q_lds[(r * 16 + l15) * 136 + ks * 32 + lg * 8];
        bf16x8 bs_ = *(bf16x8*)&St_lds[rloc * 136 + ks * 32 + lg * 8];
        f = __builtin_amdgcn_mfma_f32_16x16x32_bf16(aq, bs_, f, 0, 0, 0);
      }
#pragma unroll
      for (int rr = 0; rr < 4; rr++) f[rr] *= eG_lds[r * 16 + lg * 4 + rr];
#pragma unroll
      for (int ks2 = 0; ks2 < 2; ks2++) {
        bf16x8 ap = *(bf16x8*)&P_lds[(r * 16 + l15) * 72 + ks2 * 32 + lg * 8];
        f = __builtin_amdgcn_mfma_f32_16x16x32_bf16(ap, (ks2 == 0) ? av0 : av1, f, 0, 0, 0);
      }
      acco = f;
      const float dcv = eG_lds[63];
#pragma unroll
      for (int ni = 0; ni < 2; ni++) {
        const int ni2 = r * 2 + ni;
#pragma unroll
        for (int rr = 0; rr < 4; rr++) streg[ni][rr] *= dcv;
        bf16x8 bk0 = *(bf16x8*)&kT_lds[(ni2 * 16 + l15) * 72 + lg * 8];
        bf16x8 bk1 = *(bf16x8*)&kT_lds[(ni2 * 16 + l15) * 72 + 32 + lg * 8];
        streg[ni] = __builtin_amdgcn_mfma_f32_16x16x32_bf16(av0, bk0, streg[ni], 0, 0, 0);
        streg[ni] = __builtin_amdgcn_mfma_f32_16x16x32_bf16(av1, bk1, streg[ni], 0, 0, 0);
      }
    }
    __syncthreads();  // b4

    // ---- phase F: publish new state + so write ----
#pragma unroll
    for (int ni = 0; ni < 2; ni++) {
      const int ni2 = r * 2 + ni;
#pragma unroll
      for (int rr = 0; rr < 4; rr++)
        St_lds[(g * 16 + lg * 4 + rr) * 136 + ni2 * 16 + l15] = (bf16_t)streg[ni][rr];
    }
    {
      const int dvg = dvb * 32 + g * 16 + l15;
      const int hcol = h * 128 + dvg;  // 0..2047
#pragma unroll
      for (int rr = 0; rr < 4; rr++) {
        const int t = t0 + r * 16 + lg * 4 + rr;
        const long row = (long)b * 2048 + t;
        if (hcol < 1024)
          ((float*)qkvz)[row * 4096 + hcol] = acco[rr];
        else
          so_hi[row * 1024 + hcol - 1024] = acco[rr];
      }
    }
    // next phase A writes q/kn/kT/vT (not read after b4); St reads separated by b1+b3.
  }
}

// ---------------- RMS norm + gate(z) -> A2 (qkvz stripe [4K,8K)) ----------------
__global__ __launch_bounds__(256) void k_rmsgate(const float* __restrict__ so_hi,
                                                 bf16_t* __restrict__ qkvz,
                                                 const float* __restrict__ norm_w) {
  long row = blockIdx.x;  // b*T + t
  int tid = threadIdx.x;
  int h = tid >> 4, j = tid & 15;
  const float* srow = (h < 8) ? (const float*)qkvz + row * 4096 + h * 128 + j * 8
                              : so_hi + row * 1024 + (h - 8) * 128 + j * 8;
  float xv[8];
  *(float4*)&xv[0] = *(const float4*)srow;
  *(float4*)&xv[4] = *(const float4*)(srow + 4);
  float ss = 0.f;
#pragma unroll
  for (int e = 0; e < 8; e++) ss += xv[e] * xv[e];
  ss += __shfl_xor(ss, 1); ss += __shfl_xor(ss, 2);
  ss += __shfl_xor(ss, 4); ss += __shfl_xor(ss, 8);
  float rinv = rsqrtf(ss * (1.0f / 128.0f) + 1e-6f);
  const bf16_t* zrow = qkvz + row * 8192 + 6144 + h * 128 + j * 8;
  bf16x8 zv = *(const bf16x8*)zrow;
  bf16x8 o;
#pragma unroll
  for (int e = 0; e < 8; e++) {
    float z = (float)zv[e];
    float gate = 1.f / (1.f + __expf(-z));
    o[e] = (bf16_t)(xv[e] * rinv * norm_w[j * 8 + e] * gate);
  }
  *(bf16x8*)(qkvz + row * 8192 + 2048 + h * 128 + j * 8) = o;
}

extern "C" void kernel_launch(void* const* d_in, const int* in_sizes, int n_in,
                              void* d_out, int out_size, void* d_ws, size_t ws_size,
                              hipStream_t stream) {
  const float* x      = (const float*)d_in[0];
  // d_in[1] = positions (unused)
  const float* W_qkvz = (const float*)d_in[2];
  const float* W_b    = (const float*)d_in[3];
  const float* W_a    = (const float*)d_in[4];
  const float* conv_w = (const float*)d_in[5];
  const float* norm_w = (const float*)d_in[6];
  const float* W_out  = (const float*)d_in[7];
  float* out = (float*)d_out;
  char* ws = (char*)d_ws;

  // Workspace layout (244,580,352 bytes). qkvz row (16 KB) lifecycle:
  //  [0,4K): qkv cols (dead post-conv) -> so_lo fp32[1024] (scan -> rmsgate)
  //  [4K,8K): kT stripe (tr_kv -> scan) -> A2 bf16[2048] (rmsgate -> gemm2, lda=8192)
  //  [8K,12K): vT stripe (tr_kv -> scan)
  //  [12K,16K): z (gemm1 -> rmsgate)
  // vv: v natural (conv -> tr_kv) -> so_hi fp32 (scan -> rmsgate), 32 MB of its 33.5 MB.
  bf16_t* qkvz  = (bf16_t*)(ws + 0);
  bf16_t* xb    = (bf16_t*)(ws + 134217728);
  bf16_t* qv    = (bf16_t*)(ws + 134217728);   // aliases xb
  bf16_t* WqT   = (bf16_t*)(ws + 167772160);
  bf16_t* kv    = (bf16_t*)(ws + 167772160);   // aliases WqT
  bf16_t* vv    = (bf16_t*)(ws + 201326592);
  float*  so_hi = (float*)(ws + 201326592);    // aliases vv
  bf16_t* WoT   = (bf16_t*)(ws + 234881024);
  float*  WbT   = (float*)(ws + 243269632);
  float*  WaT   = (float*)(ws + 243400704);
  float*  beta  = (float*)(ws + 243531776);
  float*  alpha = (float*)(ws + 244056064);

  if (ws_size < 244580352) return;

  k_cast_bf16<<<8192, 256, 0, stream>>>(x, xb);
  k_transpose_cast<<<dim3(8192 / 32, 2048 / 32), dim3(32, 8), 0, stream>>>(W_qkvz, WqT, 2048, 8192);
  k_transpose_cast<<<dim3(2048 / 32, 2048 / 32), dim3(32, 8), 0, stream>>>(W_out, WoT, 2048, 2048);
  k_transpose_f32<<<8, 256, 0, stream>>>(W_b, WbT, 2048, 16);
  k_transpose_f32<<<8, 256, 0, stream>>>(W_a, WaT, 2048, 16);
  k_beta_alpha<<<8192, 256, 0, stream>>>(x, WbT, WaT, beta, alpha);
  k_gemm256<bf16_t><<<dim3(32, 32), 512, 131072, stream>>>(xb, WqT, qkvz, 8192, 2048, 2048);
  k_conv<<<8192, 256, 0, stream>>>(qkvz, conv_w, qv, kv, vv);
  k_tr_kv<<<2048, 256, 0, stream>>>(kv, vv, qkvz);
  k_scan_chunked<<<dim3(64, 4), 512, 76800, stream>>>(qv, kv, qkvz, so_hi, beta, alpha);
  k_rmsgate<<<8192, 256, 0, stream>>>(so_hi, qkvz, norm_w);
  k_gemm256<float><<<dim3(8, 32), 512, 131072, stream>>>(qkvz + 2048, WoT, out, 2048, 2048, 8192);
  (void)in_sizes; (void)n_in; (void)out_size;
}

// Round 8
// 812.501 us; speedup vs baseline: 2.6421x; 1.1260x over previous
//
#include <hip/hip_runtime.h>
#include <hip/hip_bf16.h>

typedef __bf16 bf16_t;
typedef __attribute__((ext_vector_type(8))) __bf16 bf16x8;
typedef __attribute__((ext_vector_type(4))) float floatx4;

// Problem constants: B=4, T=2048, C=2048, H=16, D=128, QKV_DIM=6144, QKVZ=8192, BT=8192

__device__ __forceinline__ void gload16(const void* g, void* l) {
  __builtin_amdgcn_global_load_lds(
      (const __attribute__((address_space(1))) void*)g,
      (__attribute__((address_space(3))) void*)l, 16, 0, 0);
}

// ---------------- cast fp32 -> bf16 (vectorized) ----------------
__global__ __launch_bounds__(256) void k_cast_bf16(const float* __restrict__ in,
                                                   bf16_t* __restrict__ out) {
  long i = ((long)blockIdx.x * 256 + threadIdx.x) * 8;
  const float4 a = *(const float4*)(in + i);
  const float4 b = *(const float4*)(in + i + 4);
  bf16x8 o;
  o[0] = (bf16_t)a.x; o[1] = (bf16_t)a.y; o[2] = (bf16_t)a.z; o[3] = (bf16_t)a.w;
  o[4] = (bf16_t)b.x; o[5] = (bf16_t)b.y; o[6] = (bf16_t)b.z; o[7] = (bf16_t)b.w;
  *(bf16x8*)(out + i) = o;
}

// ---------------- transpose + cast fp32 -> bf16 ----------------
__global__ void k_transpose_cast(const float* __restrict__ in, bf16_t* __restrict__ out,
                                 int R, int Ccols) {
  __shared__ float tile[32][33];
  int c0 = blockIdx.x * 32, r0 = blockIdx.y * 32;
  for (int i = threadIdx.y; i < 32; i += 8)
    tile[i][threadIdx.x] = in[(long)(r0 + i) * Ccols + c0 + threadIdx.x];
  __syncthreads();
  for (int i = threadIdx.y; i < 32; i += 8)
    out[(long)(c0 + i) * R + r0 + threadIdx.x] = (bf16_t)tile[threadIdx.x][i];
}

// small fp32 transpose (for W_b / W_a: 2048x16 -> 16x2048)
__global__ void k_transpose_f32(const float* __restrict__ in, float* __restrict__ out,
                                int R, int Ccols) {
  int r = blockIdx.x * blockDim.x + threadIdx.x;
  if (r < R)
    for (int c = 0; c < Ccols; ++c) out[(long)c * R + r] = in[(long)r * Ccols + c];
}

// ---------------- beta/alpha: sigmoid(x @ W) ----------------
__global__ __launch_bounds__(256) void k_beta_alpha(const float* __restrict__ x,
                                                    const float* __restrict__ WbT,
                                                    const float* __restrict__ WaT,
                                                    float* __restrict__ beta,
                                                    float* __restrict__ alpha) {
  int row = blockIdx.x;  // b*T + t
  __shared__ float xs[2048];
  for (int i = threadIdx.x; i < 2048; i += 256) xs[i] = x[(long)row * 2048 + i];
  __syncthreads();
  int wave = threadIdx.x >> 6, lane = threadIdx.x & 63;
  for (int o = wave * 8; o < wave * 8 + 8; ++o) {
    const float* W = (o < 16) ? (WbT + (long)o * 2048) : (WaT + (long)(o - 16) * 2048);
    float s = 0.f;
    for (int k2 = lane; k2 < 2048; k2 += 64) s += xs[k2] * W[k2];
    for (int off = 32; off; off >>= 1) s += __shfl_down(s, off);
    if (lane == 0) {
      float sig = 1.f / (1.f + expf(-s));
      int b = row >> 11, t = row & 2047;
      int h = (o < 16) ? o : (o - 16);
      float* dst = (o < 16) ? beta : alpha;
      dst[((long)(b * 16 + h)) * 2048 + t] = sig;
    }
  }
}

// ---------------- bf16 MFMA GEMM 256x256: C = A @ Bt^T ----------------
// A: M x K row-major bf16 (row stride lda). Bt: N x K row-major bf16 (ldb = K).
// C: M x N row-major OUT_T. BM=BN=256, BK=64, 512 threads = 8 waves (2M x 4N),
// per-wave 128x64 output = acc[8][4] 16x16 frags. LDS: double-buffered A/B tiles,
// 128 KiB, 1 block/CU. T2 swizzle: chunk (row,c) at (row, c ^ (row&7)); linear
// gload dest + inverse-permuted global source (rule 21); reads apply the XOR.
// Pipeline (T4): ONE barrier per K-step; STAGE(kt+1 -> other buffer) issued right
// after the barrier, so the next barrier's vmcnt(0) drain is covered by this
// iteration's full 64-MFMA compute phase. buf[(kt+1)&1]'s last readers were in
// iteration kt-1, already synced by barrier(kt) -> safe overwrite.
template <typename OUT_T>
__global__ __launch_bounds__(512, 2) void k_gemm256(const bf16_t* __restrict__ A,
                                                    const bf16_t* __restrict__ Bt,
                                                    OUT_T* __restrict__ C,
                                                    int N, int K, int lda) {
  extern __shared__ char gsm[];  // [buf0: A 32K | B 32K][buf1: A 32K | B 32K]
  const int m0 = blockIdx.y * 256, n0 = blockIdx.x * 256;
  const int tid = threadIdx.x;
  const int w = tid >> 6, l = tid & 63;
  const int wm = w >> 2, wn = w & 3;
  const int l15 = l & 15, lg = l >> 4;

  // staging: 4 chunks per matrix per thread; chunk id c = t*512+tid; dest byte c*16
  const bf16_t* asrc[4];
  const bf16_t* bsrc[4];
  int dofs[4];
#pragma unroll
  for (int t = 0; t < 4; ++t) {
    int c = t * 512 + tid;
    int row = c >> 3, cs = (c & 7) ^ (row & 7);  // pre-swizzled source chunk
    asrc[t] = A + (long)(m0 + row) * lda + cs * 8;
    bsrc[t] = Bt + (long)(n0 + row) * K + cs * 8;
    dofs[t] = c * 16;
  }

  auto STAGE = [&](int buf, int k0) {
    char* ab = gsm + buf * 65536;
    char* bb = ab + 32768;
#pragma unroll
    for (int t = 0; t < 4; ++t) {
      gload16(asrc[t] + k0, ab + dofs[t]);
      gload16(bsrc[t] + k0, bb + dofs[t]);
    }
  };

  floatx4 acc[8][4] = {};
  STAGE(0, 0);
  const int NK = K >> 6;
  for (int kt = 0; kt < NK; ++kt) {
    __syncthreads();  // drains stage(kt) [issued one full compute phase ago] + rendezvous
    if (kt + 1 < NK) STAGE((kt + 1) & 1, (kt + 1) << 6);  // prefetch; lands by next barrier
    const char* As_ = gsm + (kt & 1) * 65536;
    const char* Bs_ = As_ + 32768;
#pragma unroll
    for (int ks = 0; ks < 2; ++ks) {
      bf16x8 af[8], bfr[4];
#pragma unroll
      for (int mi = 0; mi < 8; ++mi) {
        const int r = wm * 128 + mi * 16 + l15;
        af[mi] = *(const bf16x8*)(As_ + r * 128 + ((((ks << 2) + lg) ^ (r & 7)) << 4));
      }
#pragma unroll
      for (int ni = 0; ni < 4; ++ni) {
        const int r = wn * 64 + ni * 16 + l15;
        bfr[ni] = *(const bf16x8*)(Bs_ + r * 128 + ((((ks << 2) + lg) ^ (r & 7)) << 4));
      }
      __builtin_amdgcn_s_setprio(1);
#pragma unroll
      for (int mi = 0; mi < 8; ++mi)
#pragma unroll
        for (int ni = 0; ni < 4; ++ni)
          acc[mi][ni] = __builtin_amdgcn_mfma_f32_16x16x32_bf16(af[mi], bfr[ni], acc[mi][ni], 0, 0, 0);
      __builtin_amdgcn_s_setprio(0);
    }
  }
  // Epilogue: C/D layout row=(l>>4)*4+r, col=l&15 [m89-verified]
  const int crow0 = m0 + wm * 128 + lg * 4;
  const int ccol = n0 + wn * 64 + l15;
#pragma unroll
  for (int mi = 0; mi < 8; ++mi)
#pragma unroll
    for (int ni = 0; ni < 4; ++ni)
#pragma unroll
      for (int r = 0; r < 4; ++r)
        C[(long)(crow0 + mi * 16 + r) * N + ccol + ni * 16] = (OUT_T)acc[mi][ni][r];
}

// ---------------- depthwise causal conv + SiLU + l2norm -> q,k,v (vectorized) ---------
__global__ __launch_bounds__(256) void k_conv(const bf16_t* __restrict__ qkvz,
                                              const float* __restrict__ conv_w,
                                              bf16_t* __restrict__ q, bf16_t* __restrict__ k,
                                              bf16_t* __restrict__ v) {
  int row = blockIdx.x;  // b*T + t
  int b = row >> 11, t = row & 2047;
  __shared__ float ys[6144];
  __shared__ float gsum[32][9];
  __shared__ float norms[32];
  const int c0 = threadIdx.x * 8;
  for (int c8 = c0; c8 < 6144; c8 += 2048) {
    bf16x8 xr[4];
#pragma unroll
    for (int w2 = 0; w2 < 4; ++w2) {
      int tt = t - 3 + w2;
      bf16x8 zr = {};
      xr[w2] = (tt >= 0) ? *(const bf16x8*)&qkvz[((long)(b * 2048 + tt)) * 8192 + c8] : zr;
    }
#pragma unroll
    for (int j = 0; j < 8; ++j) {
      float4 wv = *(const float4*)&conv_w[(c8 + j) * 4];
      float a = (float)xr[0][j] * wv.x + (float)xr[1][j] * wv.y +
                (float)xr[2][j] * wv.z + (float)xr[3][j] * wv.w;
      ys[c8 + j] = a / (1.f + __expf(-a));  // silu
    }
  }
  __syncthreads();
  {
    int g = threadIdx.x >> 3, j = threadIdx.x & 7;
    float s = 0.f;
#pragma unroll
    for (int e = 0; e < 16; ++e) {
      float yv = ys[g * 128 + j * 16 + e];
      s += yv * yv;
    }
    gsum[g][j] = s;
  }
  __syncthreads();
  if (threadIdx.x < 32) {
    float s = 0.f;
#pragma unroll
    for (int j = 0; j < 8; j++) s += gsum[threadIdx.x][j];
    norms[threadIdx.x] = 1.f / fmaxf(sqrtf(s), 1e-12f);
  }
  __syncthreads();
  for (int c8 = c0; c8 < 6144; c8 += 2048) {
    float scale;
    bf16_t* dst;
    if (c8 < 2048) {
      int h = c8 >> 7;
      scale = norms[h];
      dst = q + (((long)(b * 16 + h)) * 2048 + t) * 128 + (c8 & 127);
    } else if (c8 < 4096) {
      int h = (c8 - 2048) >> 7;
      scale = norms[16 + h];
      dst = k + (((long)(b * 16 + h)) * 2048 + t) * 128 + (c8 & 127);
    } else {
      scale = 1.f;
      int h = (c8 - 4096) >> 7;
      dst = v + (((long)(b * 16 + h)) * 2048 + t) * 128 + (c8 & 127);
    }
    bf16x8 o;
#pragma unroll
    for (int j = 0; j < 8; ++j) o[j] = (bf16_t)(ys[c8 + j] * scale);
    *(bf16x8*)dst = o;
  }
}

// ---------------- k,v natural -> kT,vT stripes inside dead qkvz region ----------------
// kT element (bh,dk,t) at qkvz elem (bh*128+dk)*8192 + 2048 + t
// vT element (bh,dv,t) at qkvz elem (bh*128+dv)*8192 + 4096 + t
__global__ __launch_bounds__(256) void k_tr_kv(const bf16_t* __restrict__ kv,
                                               const bf16_t* __restrict__ vv,
                                               bf16_t* __restrict__ qkvz) {
  __shared__ bf16_t t_lds[64 * 136];
  int bh = blockIdx.x >> 5, tc = blockIdx.x & 31;
  int t0 = tc * 64;
  int tid = threadIdx.x;
#pragma unroll
  for (int pass = 0; pass < 2; ++pass) {
    const bf16_t* src = (pass == 0 ? kv : vv) + (long)bh * 2048 * 128 + (long)t0 * 128;
    int r = tid >> 2, sc = (tid & 3) * 32;
    bf16x8 x0 = *(const bf16x8*)(src + (long)r * 128 + sc);
    bf16x8 x1 = *(const bf16x8*)(src + (long)r * 128 + sc + 8);
    bf16x8 x2 = *(const bf16x8*)(src + (long)r * 128 + sc + 16);
    bf16x8 x3 = *(const bf16x8*)(src + (long)r * 128 + sc + 24);
    __syncthreads();
    *(bf16x8*)&t_lds[r * 136 + sc] = x0;
    *(bf16x8*)&t_lds[r * 136 + sc + 8] = x1;
    *(bf16x8*)&t_lds[r * 136 + sc + 16] = x2;
    *(bf16x8*)&t_lds[r * 136 + sc + 24] = x3;
    __syncthreads();
    int d = tid >> 1, h2 = tid & 1;
    bf16_t* dst = qkvz + (long)(bh * 128 + d) * 8192 + (pass ? 4096 : 2048) + t0 + h2 * 32;
#pragma unroll
    for (int g = 0; g < 4; ++g) {
      bf16x8 o;
#pragma unroll
      for (int j = 0; j < 8; ++j) o[j] = t_lds[(h2 * 32 + g * 8 + j) * 136 + d];
      *(bf16x8*)(dst + g * 8) = o;
    }
  }
}

// ---------------- fused chunked gated-linear-attention scan (dv-split 4-way) ----------
// Grid (64 bh, 4 dvb), 512 threads = 8 waves. Wave w: g=w&1 (dv group of 16 rows within
// the block's 32-dv quarter), r=w>>1 (role: splits t-tiles mi and dk-tiles ni2).
// so output fp32: h<8 -> qkvz row stripe [0,4K) as fp32[1024]; h>=8 -> so_hi (vv) [1024]/row.
__global__ __launch_bounds__(512, 1) void k_scan_chunked(
    const bf16_t* __restrict__ qv, const bf16_t* __restrict__ kv,
    bf16_t* __restrict__ qkvz, float* __restrict__ so_hi,
    const float* __restrict__ beta, const float* __restrict__ alpha) {
  extern __shared__ char smem[];
  bf16_t* q_lds = (bf16_t*)smem;            // [64][136] = 17408 B
  bf16_t* kn_lds = q_lds + 8704;            // [64][136]
  bf16_t* kT_lds = kn_lds + 8704;           // [128][72] = 18432 B
  bf16_t* vT_lds = kT_lds + 9216;           // [32][72]  = 4608 B
  bf16_t* P_lds = vT_lds + 2304;            // [64][72]  = 9216 B
  bf16_t* St_lds = P_lds + 4608;            // [32][136] = 8704 B
  float* G_lds = (float*)(St_lds + 4352);   // [64]
  float* bet_lds = G_lds + 64;              // [64]
  float* w_lds = bet_lds + 64;              // [64] beta_s * exp(Gend - G_s)
  float* eG_lds = w_lds + 64;               // [64] exp(G_t)

  const int bh = blockIdx.x, dvb = blockIdx.y;
  const int b = bh >> 4, h = bh & 15;
  const int tid = threadIdx.x;
  const int w = tid >> 6, l = tid & 63;
  const int l15 = l & 15, lg = l >> 4;
  const int g = w & 1, r = w >> 1;

  const bf16_t* qb = qv + (long)bh * 2048 * 128;
  const bf16_t* kb = kv + (long)bh * 2048 * 128;
  const bf16_t* kTg = qkvz + (long)bh * 128 * 8192 + 2048;
  const bf16_t* vTg = qkvz + (long)(bh * 128 + dvb * 32) * 8192 + 4096;
  const float* bet = beta + (long)bh * 2048;
  const float* alp = alpha + (long)bh * 2048;

  floatx4 streg[2] = {};
  for (int i = tid; i < 2176; i += 512) ((float*)St_lds)[i] = 0.f;
  __syncthreads();

  const int sr = tid >> 3, ssc = (tid & 7) * 16;    // q/kn: 64 x 128
  const int sdk = tid >> 2, ssc2 = (tid & 3) * 16;  // kT: 128 x 64

  for (int c = 0; c < 32; ++c) {
    const int t0 = c * 64;
    // ---- phase A: stage tiles + (wave0) decay math ----
    {
      const bf16_t* qs = qb + (long)(t0 + sr) * 128 + ssc;
      const bf16_t* ks = kb + (long)(t0 + sr) * 128 + ssc;
      const bf16_t* kts = kTg + (long)sdk * 8192 + t0 + ssc2;
      bf16x8 a0 = *(const bf16x8*)qs, a1 = *(const bf16x8*)(qs + 8);
      bf16x8 b0 = *(const bf16x8*)ks, b1 = *(const bf16x8*)(ks + 8);
      bf16x8 c0 = *(const bf16x8*)kts, c1 = *(const bf16x8*)(kts + 8);
      *(bf16x8*)&q_lds[sr * 136 + ssc] = a0;
      *(bf16x8*)&q_lds[sr * 136 + ssc + 8] = a1;
      *(bf16x8*)&kn_lds[sr * 136 + ssc] = b0;
      *(bf16x8*)&kn_lds[sr * 136 + ssc + 8] = b1;
      *(bf16x8*)&kT_lds[sdk * 72 + ssc2] = c0;
      *(bf16x8*)&kT_lds[sdk * 72 + ssc2 + 8] = c1;
      if (tid < 256) {
        int svr = tid >> 3, svc = (tid & 7) * 8;
        bf16x8 d0 = *(const bf16x8*)(vTg + (long)svr * 8192 + t0 + svc);
        *(bf16x8*)&vT_lds[svr * 72 + svc] = d0;
      }
      if (w == 0) {
        float bsv = bet[t0 + l];
        float la = __logf(alp[t0 + l]);
#pragma unroll
        for (int off = 1; off < 64; off <<= 1) {
          float xup = __shfl_up(la, off);
          if (l >= off) la += xup;
        }
        float ge = __shfl(la, 63);
        G_lds[l] = la;
        bet_lds[l] = bsv;
        w_lds[l] = bsv * __expf(ge - la);
        eG_lds[l] = __expf(la);
      }
    }
    __syncthreads();  // b1

    // ---- phase B: scale kT in place (each thread scales what it staged) ----
    {
      bf16_t* p = &kT_lds[sdk * 72 + ssc2];
      bf16x8 x0 = *(bf16x8*)p, x1 = *(bf16x8*)(p + 8);
#pragma unroll
      for (int j = 0; j < 8; j++) {
        x0[j] = (bf16_t)((float)x0[j] * w_lds[ssc2 + j]);
        x1[j] = (bf16_t)((float)x1[j] * w_lds[ssc2 + 8 + j]);
      }
      *(bf16x8*)p = x0;
      *(bf16x8*)(p + 8) = x1;
    }

    // ---- phase CD: score = q K^T (2 tiles/wave), build P ----
    {
      const int mi = w >> 1;
      bf16x8 aq[4];
#pragma unroll
      for (int ks = 0; ks < 4; ks++)
        aq[ks] = *(bf16x8*)&q_lds[(mi * 16 + l15) * 136 + ks * 32 + lg * 8];
#pragma unroll
      for (int sn2 = 0; sn2 < 2; sn2++) {
        const int sn = (w & 1) * 2 + sn2;
        floatx4 sc_ = {0.f, 0.f, 0.f, 0.f};
#pragma unroll
        for (int ks = 0; ks < 4; ks++) {
          bf16x8 bk = *(bf16x8*)&kn_lds[(sn * 16 + l15) * 136 + ks * 32 + lg * 8];
          sc_ = __builtin_amdgcn_mfma_f32_16x16x32_bf16(aq[ks], bk, sc_, 0, 0, 0);
        }
        const int sl = sn * 16 + l15;
        const float gs = G_lds[sl], bs = bet_lds[sl];
#pragma unroll
        for (int rr = 0; rr < 4; rr++) {
          const int tl = mi * 16 + lg * 4 + rr;
          float val = (sl <= tl) ? sc_[rr] * __expf(G_lds[tl] - gs) * bs : 0.f;
          P_lds[tl * 72 + sl] = (bf16_t)val;
        }
      }
    }
    __syncthreads();  // b3

    // ---- phase E: out(mi=r) = exp(Gt)*(q@S_in) + P@V ; state update (ni2 = 2r,2r+1) ----
    floatx4 acco = {0.f, 0.f, 0.f, 0.f};
    {
      const int rloc = g * 16 + l15;  // local dv row (block quarter)
      bf16x8 av0 = *(bf16x8*)&vT_lds[rloc * 72 + lg * 8];
      bf16x8 av1 = *(bf16x8*)&vT_lds[rloc * 72 + 32 + lg * 8];
      floatx4 f = {0.f, 0.f, 0.f, 0.f};
#pragma unroll
      for (int ks = 0; ks < 4; ks++) {
        bf16x8 aq = *(bf16x8*)&q_lds[(r * 16 + l15) * 136 + ks * 32 + lg * 8];
        bf16x8 bs_ = *(bf16x8*)&St_lds[rloc * 136 + ks * 32 + lg * 8];
        f = __builtin_amdgcn_mfma_f32_16x16x32_bf16(aq, bs_, f, 0, 0, 0);
      }
#pragma unroll
      for (int rr = 0; rr < 4; rr++) f[rr] *= eG_lds[r * 16 + lg * 4 + rr];
#pragma unroll
      for (int ks2 = 0; ks2 < 2; ks2++) {
        bf16x8 ap = *(bf16x8*)&P_lds[(r * 16 + l15) * 72 + ks2 * 32 + lg * 8];
        f = __builtin_amdgcn_mfma_f32_16x16x32_bf16(ap, (ks2 == 0) ? av0 : av1, f, 0, 0, 0);
      }
      acco = f;
      const float dcv = eG_lds[63];
#pragma unroll
      for (int ni = 0; ni < 2; ni++) {
        const int ni2 = r * 2 + ni;
#pragma unroll
        for (int rr = 0; rr < 4; rr++) streg[ni][rr] *= dcv;
        bf16x8 bk0 = *(bf16x8*)&kT_lds[(ni2 * 16 + l15) * 72 + lg * 8];
        bf16x8 bk1 = *(bf16x8*)&kT_lds[(ni2 * 16 + l15) * 72 + 32 + lg * 8];
        streg[ni] = __builtin_amdgcn_mfma_f32_16x16x32_bf16(av0, bk0, streg[ni], 0, 0, 0);
        streg[ni] = __builtin_amdgcn_mfma_f32_16x16x32_bf16(av1, bk1, streg[ni], 0, 0, 0);
      }
    }
    __syncthreads();  // b4

    // ---- phase F: publish new state + so write ----
#pragma unroll
    for (int ni = 0; ni < 2; ni++) {
      const int ni2 = r * 2 + ni;
#pragma unroll
      for (int rr = 0; rr < 4; rr++)
        St_lds[(g * 16 + lg * 4 + rr) * 136 + ni2 * 16 + l15] = (bf16_t)streg[ni][rr];
    }
    {
      const int dvg = dvb * 32 + g * 16 + l15;
      const int hcol = h * 128 + dvg;  // 0..2047
#pragma unroll
      for (int rr = 0; rr < 4; rr++) {
        const int t = t0 + r * 16 + lg * 4 + rr;
        const long row = (long)b * 2048 + t;
        if (hcol < 1024)
          ((float*)qkvz)[row * 4096 + hcol] = acco[rr];
        else
          so_hi[row * 1024 + hcol - 1024] = acco[rr];
      }
    }
    // next phase A writes q/kn/kT/vT (not read after b4); St reads separated by b1+b3.
  }
}

// ---------------- RMS norm + gate(z) -> A2 (contiguous, in dead qv buffer) -----------
__global__ __launch_bounds__(256) void k_rmsgate(const float* __restrict__ so_hi,
                                                 const bf16_t* __restrict__ qkvz,
                                                 bf16_t* __restrict__ A2,
                                                 const float* __restrict__ norm_w) {
  long row = blockIdx.x;  // b*T + t
  int tid = threadIdx.x;
  int h = tid >> 4, j = tid & 15;
  const float* srow = (h < 8) ? (const float*)qkvz + row * 4096 + h * 128 + j * 8
                              : so_hi + row * 1024 + (h - 8) * 128 + j * 8;
  float xv[8];
  *(float4*)&xv[0] = *(const float4*)srow;
  *(float4*)&xv[4] = *(const float4*)(srow + 4);
  float ss = 0.f;
#pragma unroll
  for (int e = 0; e < 8; e++) ss += xv[e] * xv[e];
  ss += __shfl_xor(ss, 1); ss += __shfl_xor(ss, 2);
  ss += __shfl_xor(ss, 4); ss += __shfl_xor(ss, 8);
  float rinv = rsqrtf(ss * (1.0f / 128.0f) + 1e-6f);
  const bf16_t* zrow = qkvz + row * 8192 + 6144 + h * 128 + j * 8;
  bf16x8 zv = *(const bf16x8*)zrow;
  bf16x8 o;
#pragma unroll
  for (int e = 0; e < 8; e++) {
    float z = (float)zv[e];
    float gate = 1.f / (1.f + __expf(-z));
    o[e] = (bf16_t)(xv[e] * rinv * norm_w[j * 8 + e] * gate);
  }
  *(bf16x8*)(A2 + row * 2048 + h * 128 + j * 8) = o;
}

extern "C" void kernel_launch(void* const* d_in, const int* in_sizes, int n_in,
                              void* d_out, int out_size, void* d_ws, size_t ws_size,
                              hipStream_t stream) {
  const float* x      = (const float*)d_in[0];
  // d_in[1] = positions (unused)
  const float* W_qkvz = (const float*)d_in[2];
  const float* W_b    = (const float*)d_in[3];
  const float* W_a    = (const float*)d_in[4];
  const float* conv_w = (const float*)d_in[5];
  const float* norm_w = (const float*)d_in[6];
  const float* W_out  = (const float*)d_in[7];
  float* out = (float*)d_out;
  char* ws = (char*)d_ws;

  // Workspace layout (244,580,352 bytes). qkvz row (16 KB) lifecycle:
  //  [0,4K): qkv cols (dead post-conv) -> so_lo fp32[1024] (scan -> rmsgate)
  //  [4K,8K): kT stripe (tr_kv -> scan)
  //  [8K,12K): vT stripe (tr_kv -> scan)
  //  [12K,16K): z (gemm1 -> rmsgate)
  // xb/qv region: xb (cast -> gemm1), qv (conv -> scan), A2 contiguous (rmsgate -> gemm2).
  // vv: v natural (conv -> tr_kv) -> so_hi fp32 (scan -> rmsgate).
  bf16_t* qkvz  = (bf16_t*)(ws + 0);
  bf16_t* xb    = (bf16_t*)(ws + 134217728);
  bf16_t* qv    = (bf16_t*)(ws + 134217728);   // aliases xb
  bf16_t* A2    = (bf16_t*)(ws + 134217728);   // aliases qv (dead after scan)
  bf16_t* WqT   = (bf16_t*)(ws + 167772160);
  bf16_t* kv    = (bf16_t*)(ws + 167772160);   // aliases WqT
  bf16_t* vv    = (bf16_t*)(ws + 201326592);
  float*  so_hi = (float*)(ws + 201326592);    // aliases vv
  bf16_t* WoT   = (bf16_t*)(ws + 234881024);
  float*  WbT   = (float*)(ws + 243269632);
  float*  WaT   = (float*)(ws + 243400704);
  float*  beta  = (float*)(ws + 243531776);
  float*  alpha = (float*)(ws + 244056064);

  if (ws_size < 244580352) return;

  k_cast_bf16<<<8192, 256, 0, stream>>>(x, xb);
  k_transpose_cast<<<dim3(8192 / 32, 2048 / 32), dim3(32, 8), 0, stream>>>(W_qkvz, WqT, 2048, 8192);
  k_transpose_cast<<<dim3(2048 / 32, 2048 / 32), dim3(32, 8), 0, stream>>>(W_out, WoT, 2048, 2048);
  k_transpose_f32<<<8, 256, 0, stream>>>(W_b, WbT, 2048, 16);
  k_transpose_f32<<<8, 256, 0, stream>>>(W_a, WaT, 2048, 16);
  k_beta_alpha<<<8192, 256, 0, stream>>>(x, WbT, WaT, beta, alpha);
  k_gemm256<bf16_t><<<dim3(32, 32), 512, 131072, stream>>>(xb, WqT, qkvz, 8192, 2048, 2048);
  k_conv<<<8192, 256, 0, stream>>>(qkvz, conv_w, qv, kv, vv);
  k_tr_kv<<<2048, 256, 0, stream>>>(kv, vv, qkvz);
  k_scan_chunked<<<dim3(64, 4), 512, 76800, stream>>>(qv, kv, qkvz, so_hi, beta, alpha);
  k_rmsgate<<<8192, 256, 0, stream>>>(so_hi, qkvz, A2, norm_w);
  k_gemm256<float><<<dim3(8, 32), 512, 131072, stream>>>(A2, WoT, out, 2048, 2048, 2048);
  (void)in_sizes; (void)n_in; (void)out_size;
}